// Round 13
// baseline (811.419 us; speedup 1.0000x reference)
//
#include <hip/hip_runtime.h>

#define ANG 9
#define HH 96
#define BB 2
#define PLANE_F (81*HH*HH)  // 746496 per channel (81 views x 96x96)
#define PLANE_A (HH*HH)     // 9216
#define NBLK_FEAT 972       // BB*81*6 blocks (each: 384 threads, 16-row strip)
#define LROW 98             // LDS padded row length (zero cols at 0 and 97)
#define LTILE (18*LROW)     // 18 halo rows

// ===== generic BN-final: reduce per-block partials -> scale/shift =====
__global__ __launch_bounds__(256) void k_bnfinal(const float* __restrict__ psum,
    const float* __restrict__ psq, const float* __restrict__ g, const float* __restrict__ bbias,
    float* __restrict__ sc, float* __restrict__ sh, int NB, float invN) {
  int c = blockIdx.x, tid = threadIdx.x;
  float s = 0.f, q = 0.f;
  for (int k = tid; k < NB; k += 256) { s += psum[c * NB + k]; q += psq[c * NB + k]; }
  __shared__ float ss[256], qq[256];
  ss[tid] = s; qq[tid] = q;
  __syncthreads();
  for (int st = 128; st > 0; st >>= 1) {
    if (tid < st) { ss[tid] += ss[tid + st]; qq[tid] += qq[tid + st]; }
    __syncthreads();
  }
  if (tid == 0) {
    float mean = ss[0] * invN;
    float var = fmaxf(qq[0] * invN - mean * mean, 0.f);
    float scale = g[c] / sqrtf(var + 1e-5f);
    sc[c] = scale; sh[c] = bbias[c] - mean * scale;
  }
}

// ===== weight prep: BuildCost shuffle + pointwise transposes, one dispatch =====
__global__ __launch_bounds__(256) void k_wprep(const float* __restrict__ bcw,
    const float* __restrict__ a0pw, const float* __restrict__ ampw, const float* __restrict__ lpw,
    float* __restrict__ wt, float* __restrict__ wpt) {
  int k = blockIdx.x * 256 + threadIdx.x;
  if (k < 81648) {
    int o = k & 15; int rest = k >> 4;
    int r81 = rest % 81; int gc = rest / 81;
    int c = gc % 7, g = gc / 7;
    wt[k] = bcw[((g * 16 + o) * 7 + c) * 81 + r81];
    return;
  }
  int t = k - 81648;
  if (t < 25920) {                                   // a0pw [180][144] -> [c][o]
    int c = t / 180, o = t % 180;
    wpt[t] = a0pw[o * 144 + c];
  } else if (t < 25920 + 129600) {                   // ampw [m][180][180] -> [m][c][o]
    int t2 = t - 25920;
    int m = t2 / 32400, r = t2 % 32400;
    int c = r / 180, o = r % 180;
    wpt[t] = ampw[m * 32400 + o * 180 + c];
  } else if (t < 25920 + 129600 + 1620) {            // lpw [9][180] -> [c][o]
    int t2 = t - 25920 - 129600;
    int c = t2 / 9, o = t2 % 9;
    wpt[t] = lpw[o * 180 + c];
  }
}

// ===== shared epilogue: per-block stats reduce (384 thr = 6 waves) =====
__device__ __forceinline__ void feat_stats(float (&acc)[4][7], float* __restrict__ psum,
    float* __restrict__ psq, int blk, int tid) {
  float sv[7], qv[7];
  #pragma unroll
  for (int o = 0; o < 7; o++) {
    sv[o] = acc[0][o] + acc[1][o] + acc[2][o] + acc[3][o];
    qv[o] = acc[0][o]*acc[0][o] + acc[1][o]*acc[1][o] + acc[2][o]*acc[2][o] + acc[3][o]*acc[3][o];
  }
  #pragma unroll
  for (int off2 = 32; off2 > 0; off2 >>= 1)
    #pragma unroll
    for (int o = 0; o < 7; o++) { sv[o] += __shfl_down(sv[o], off2); qv[o] += __shfl_down(qv[o], off2); }
  __shared__ float red[6][14];
  int wave = tid >> 6, lane = tid & 63;
  if (lane == 0) {
    #pragma unroll
    for (int o = 0; o < 7; o++) { red[wave][o] = sv[o]; red[wave][7 + o] = qv[o]; }
  }
  __syncthreads();
  if (tid < 14) {
    float t6 = red[0][tid] + red[1][tid] + red[2][tid] + red[3][tid] + red[4][tid] + red[5][tid];
    if (tid < 7) psum[tid * NBLK_FEAT + blk] = t6;
    else         psq[(tid - 7) * NBLK_FEAT + blk] = t6;
  }
}

// ===== feature conv0: 1->7 from raw x, LDS halo tile (padding baked in) =====
// grid NBLK_FEAT=972, block 384: blk -> strip = blk%6, uv = (blk/6)%81, b = blk/486
__global__ __launch_bounds__(384) void k_featconv0(const float* __restrict__ x,
    const float* __restrict__ w, float* __restrict__ out,
    float* __restrict__ psum, float* __restrict__ psq) {
  __shared__ float buf[LTILE];
  int blk = blockIdx.x, tid = threadIdx.x;
  int strip = blk % 6; int view = blk / 6;
  int uv = view % 81, b = view / 81;
  int u = uv / 9, v = uv % 9;
  int j = tid % HH, ir = tid / HH;                   // ir in [0,4)
  const float* bx = x + (size_t)b * PLANE_F + (u * HH) * 864 + v * HH;
  // stage raw tile with zero halo (implements pad=1)
  for (int idx = tid; idx < LTILE; idx += 384) {
    int lr = idx / LROW, lc = idx - lr * LROW;
    int gr = strip * 16 + lr - 1, gc = lc - 1;
    float mv = ((unsigned)gr < 96u && (unsigned)gc < 96u) ? 1.f : 0.f;
    int grc = min(max(gr, 0), 95), gcc = min(max(gc, 0), 95);
    buf[idx] = bx[grc * 864 + gcc] * mv;
  }
  __syncthreads();
  float win[6][3];
  #pragma unroll
  for (int r6 = 0; r6 < 6; r6++)
    #pragma unroll
    for (int dx = 0; dx < 3; dx++)
      win[r6][dx] = buf[(ir * 4 + r6) * LROW + j + dx];
  float acc[4][7];
  #pragma unroll
  for (int px = 0; px < 4; px++)
    #pragma unroll
    for (int o = 0; o < 7; o++) acc[px][o] = 0.f;
  #pragma unroll
  for (int o = 0; o < 7; o++) {
    const float* wc = w + o * 9;
    #pragma unroll
    for (int ky = 0; ky < 3; ky++)
      #pragma unroll
      for (int kx = 0; kx < 3; kx++) {
        float wv = wc[ky * 3 + kx];
        #pragma unroll
        for (int px = 0; px < 4; px++)
          acc[px][o] = fmaf(win[px + ky][kx], wv, acc[px][o]);
      }
  }
  int i0 = strip * 16 + ir * 4;
  #pragma unroll
  for (int o = 0; o < 7; o++) {
    float* op = out + ((size_t)(b * 7 + o)) * PLANE_F + uv * PLANE_A + i0 * HH + j;
    #pragma unroll
    for (int px = 0; px < 4; px++) op[px * HH] = acc[px][o];
  }
  __syncthreads();
  feat_stats(acc, psum, psq, blk, tid);
}

// ===== feature conv: 7->7, LDS halo tile double-buffered, BN+ReLU at staging =====
__global__ __launch_bounds__(384) void k_featconv4(const float* __restrict__ in,
    const float* __restrict__ w, const float* __restrict__ sc, const float* __restrict__ sh,
    float* __restrict__ out, float* __restrict__ psum, float* __restrict__ psq) {
  __shared__ float buf[2][LTILE];
  int blk = blockIdx.x, tid = threadIdx.x;
  int strip = blk % 6; int view = blk / 6;
  int uv = view % 81, b = view / 81;
  int j = tid % HH, ir = tid / HH;
  const float* ipbase = in + ((size_t)(b * 7)) * PLANE_F + uv * PLANE_A;
  // stage channel 0 (BN+ReLU applied; zero halo)
  {
    float s = sc[0], h2 = sh[0];
    const float* ip = ipbase;
    for (int idx = tid; idx < LTILE; idx += 384) {
      int lr = idx / LROW, lc = idx - lr * LROW;
      int gr = strip * 16 + lr - 1, gc = lc - 1;
      float mv = ((unsigned)gr < 96u && (unsigned)gc < 96u) ? 1.f : 0.f;
      int grc = min(max(gr, 0), 95), gcc = min(max(gc, 0), 95);
      buf[0][idx] = fmaxf(fmaf(ip[grc * HH + gcc], s, h2), 0.f) * mv;
    }
  }
  __syncthreads();
  float acc[4][7];
  #pragma unroll
  for (int px = 0; px < 4; px++)
    #pragma unroll
    for (int o = 0; o < 7; o++) acc[px][o] = 0.f;
  #pragma unroll 1
  for (int c = 0; c < 7; c++) {
    int pb = c & 1;
    // window from staged buffer
    float win[6][3];
    #pragma unroll
    for (int r6 = 0; r6 < 6; r6++)
      #pragma unroll
      for (int dx = 0; dx < 3; dx++)
        win[r6][dx] = buf[pb][(ir * 4 + r6) * LROW + j + dx];
    // stage next channel into the other buffer (overlaps with compute below)
    if (c < 6) {
      float s = sc[c + 1], h2 = sh[c + 1];
      const float* ip = ipbase + (size_t)(c + 1) * PLANE_F;
      for (int idx = tid; idx < LTILE; idx += 384) {
        int lr = idx / LROW, lc = idx - lr * LROW;
        int gr = strip * 16 + lr - 1, gc = lc - 1;
        float mv = ((unsigned)gr < 96u && (unsigned)gc < 96u) ? 1.f : 0.f;
        int grc = min(max(gr, 0), 95), gcc = min(max(gc, 0), 95);
        buf[pb ^ 1][idx] = fmaxf(fmaf(ip[grc * HH + gcc], s, h2), 0.f) * mv;
      }
    }
    #pragma unroll
    for (int o = 0; o < 7; o++) {
      const float* wc = w + (o * 7 + c) * 9;
      #pragma unroll
      for (int ky = 0; ky < 3; ky++)
        #pragma unroll
        for (int kx = 0; kx < 3; kx++) {
          float wv = wc[ky * 3 + kx];
          #pragma unroll
          for (int px = 0; px < 4; px++)
            acc[px][o] = fmaf(win[px + ky][kx], wv, acc[px][o]);
        }
    }
    __syncthreads();
  }
  int i0 = strip * 16 + ir * 4;
  #pragma unroll
  for (int o = 0; o < 7; o++) {
    float* op = out + ((size_t)(b * 7 + o)) * PLANE_F + uv * PLANE_A + i0 * HH + j;
    #pragma unroll
    for (int px = 0; px < 4; px++) op[px * HH] = acc[px][o];
  }
  feat_stats(acc, psum, psq, blk, tid);
}

// ===== BuildCost helper: branchless clamped 9-tap load (R6-proven) =====
__device__ __forceinline__ void bc_load(const float* __restrict__ F, int b, int c, int u,
    int d, int i, int j, float* raw, float* msk) {
  const float* Fc = F + ((size_t)(b * 7 + c)) * PLANE_F + (u * 9) * PLANE_A;
  int ii = i + d * (4 - u);
  float mi = ((unsigned)ii < 96u) ? 1.f : 0.f;
  int iic = min(max(ii, 0), 95);
  const float* Frow = Fc + iic * HH;
  #pragma unroll
  for (int v = 0; v < 9; v++) {
    int jj = j + d * (4 - v);
    float mj = ((unsigned)jj < 96u) ? 1.f : 0.f;
    int jjc = min(max(jj, 0), 95);
    raw[v] = Frow[v * PLANE_A + jjc];
    msk[v] = mi * mj;
  }
}

// ===== BuildCost: 8-o split, SGPR weights, prefetched branchless loads (R6) =====
// grid (18, 36, 2): x = gg (g*2+half, fastest for L3 reuse), y = pos block, z = b
__global__ __launch_bounds__(256) void k_buildcost(const float* __restrict__ F,
    const float* __restrict__ sc, const float* __restrict__ sh,
    const float* __restrict__ wt, float* __restrict__ cv) {
  int gg = blockIdx.x, b = blockIdx.z, tid = threadIdx.x;
  int g = gg >> 1, half = gg & 1;
  int d = g - 4;
  bool flip = d > 0;
  int p = blockIdx.y * 256 + tid;
  int i = p / HH, j = p % HH;
  float acc[8];
  #pragma unroll
  for (int o = 0; o < 8; o++) acc[o] = 0.f;
  float raw[9], msk[9];
  bc_load(F, b, 0, 0, d, i, j, raw, msk);
  #pragma unroll 1
  for (int cu = 0; cu < 63; cu++) {
    int c = cu / 9, u = cu - c * 9;
    float cr[9], cm[9];
    #pragma unroll
    for (int v = 0; v < 9; v++) { cr[v] = raw[v]; cm[v] = msk[v]; }
    if (cu + 1 < 63) {
      int cn = (cu + 1) / 9, un = (cu + 1) - cn * 9;
      bc_load(F, b, cn, un, d, i, j, raw, msk);
    }
    float s = sc[c], h2 = sh[c];
    int uw = flip ? 8 - u : u;
    const float* wbase = wt + ((size_t)((g * 7 + c) * 81 + uw * 9)) * 16 + half * 8;
    #pragma unroll
    for (int v = 0; v < 9; v++) {
      float a = fmaxf(fmaf(cr[v], s, h2), 0.f) * cm[v];
      int vw = flip ? 8 - v : v;
      const float* wp = wbase + vw * 16;            // uniform -> s_load
      #pragma unroll
      for (int o = 0; o < 8; o++) acc[o] = fmaf(wp[o], a, acc[o]);
    }
  }
  size_t cvb = ((size_t)(b * 144 + g * 16 + half * 8)) * PLANE_A + p;
  #pragma unroll
  for (int o = 0; o < 8; o++) cv[cvb + o * PLANE_A] = acc[o];
}

// ===== depthwise 3x3: 4-row strips, block-uniform channel (SGPR weights) =====
// grid: BB*C*9 blocks; blk = (b*C + c)*9 + q. Stats: psum[c*18 + b*9 + q].
template<bool AFF>
__global__ __launch_bounds__(256) void k_dwconv(const float* __restrict__ in,
    const float* __restrict__ w, const float* __restrict__ isc, const float* __restrict__ ish,
    float* __restrict__ out, float* __restrict__ psum, float* __restrict__ psq, int C) {
  int blk = blockIdx.x, tid = threadIdx.x;
  int q = blk % 9; int rr = blk / 9; int c = rr % C; int b = rr / C;
  int widx = q * 256 + tid;
  int j = widx % HH, i0 = (widx / HH) * 4;
  float s  = AFF ? isc[c] : 1.f;                    // uniform -> s_load
  float h2 = AFF ? ish[c] : 0.f;
  const float* wc = w + c * 9;                      // uniform -> s_load
  const float* ip = in + ((size_t)(b * C + c)) * PLANE_A;
  int off[6][3]; float m[6][3];
  #pragma unroll
  for (int r6 = 0; r6 < 6; r6++) {
    int ii = i0 + r6 - 1;
    float mi = ((unsigned)ii < 96u) ? 1.f : 0.f;
    int iic = min(max(ii, 0), 95);
    #pragma unroll
    for (int dx = 0; dx < 3; dx++) {
      int jj = j + dx - 1;
      float mj = ((unsigned)jj < 96u) ? 1.f : 0.f;
      int jjc = min(max(jj, 0), 95);
      off[r6][dx] = iic * HH + jjc;
      m[r6][dx] = mi * mj;
    }
  }
  float win[6][3];
  #pragma unroll
  for (int r6 = 0; r6 < 6; r6++)
    #pragma unroll
    for (int dx = 0; dx < 3; dx++) {
      float vv = ip[off[r6][dx]];
      if (AFF) vv = fmaxf(fmaf(vv, s, h2), 0.f);
      win[r6][dx] = vv * m[r6][dx];
    }
  float acc[4];
  #pragma unroll
  for (int px = 0; px < 4; px++) acc[px] = 0.f;
  #pragma unroll
  for (int ky = 0; ky < 3; ky++)
    #pragma unroll
    for (int kx = 0; kx < 3; kx++) {
      float wv = wc[ky * 3 + kx];
      #pragma unroll
      for (int px = 0; px < 4; px++)
        acc[px] = fmaf(win[px + ky][kx], wv, acc[px]);
    }
  float* op = out + ((size_t)(b * C + c)) * PLANE_A + i0 * HH + j;
  #pragma unroll
  for (int px = 0; px < 4; px++) op[px * HH] = acc[px];
  float sv = acc[0] + acc[1] + acc[2] + acc[3];
  float qv = acc[0]*acc[0] + acc[1]*acc[1] + acc[2]*acc[2] + acc[3]*acc[3];
  #pragma unroll
  for (int off2 = 32; off2 > 0; off2 >>= 1) { sv += __shfl_down(sv, off2); qv += __shfl_down(qv, off2); }
  __shared__ float red[4][2];
  int wave = tid >> 6, lane = tid & 63;
  if (lane == 0) { red[wave][0] = sv; red[wave][1] = qv; }
  __syncthreads();
  if (tid == 0) {
    float S = red[0][0] + red[1][0] + red[2][0] + red[3][0];
    float Q = red[0][1] + red[1][1] + red[2][1] + red[3][1];
    psum[c * 18 + b * 9 + q] = S;
    psq [c * 18 + b * 9 + q] = Q;
  }
}

// ===== pointwise conv: 18 out/thread, transposed weights (contiguous s_load) =====
// grid (10, 72): x = output group (18 outputs), y = position block
template<int K>
__global__ __launch_bounds__(256) void k_pwconv(const float* __restrict__ in,
    const float* __restrict__ sc, const float* __restrict__ sh,
    const float* __restrict__ wpt, float* __restrict__ out,
    float* __restrict__ psum, float* __restrict__ psq) {
  int tid = threadIdx.x;
  int posblk = blockIdx.y;
  int p = posblk * 256 + tid;
  int b = p / PLANE_A, pp = p - b * PLANE_A;
  int obase = blockIdx.x * 18;
  float acc[18];
  #pragma unroll
  for (int o = 0; o < 18; o++) acc[o] = 0.f;
  const float* ib = in + (size_t)b * K * PLANE_A + pp;
  float xn[4];
  #pragma unroll
  for (int q2 = 0; q2 < 4; q2++) xn[q2] = ib[(size_t)q2 * PLANE_A];
  #pragma unroll 1
  for (int c0 = 0; c0 < K; c0 += 4) {
    float xv[4];
    #pragma unroll
    for (int q2 = 0; q2 < 4; q2++) xv[q2] = xn[q2];
    if (c0 + 4 < K) {
      #pragma unroll
      for (int q2 = 0; q2 < 4; q2++) xn[q2] = ib[(size_t)(c0 + 4 + q2) * PLANE_A];
    }
    #pragma unroll
    for (int q2 = 0; q2 < 4; q2++) {
      int c = c0 + q2;
      float v = fmaxf(fmaf(xv[q2], sc[c], sh[c]), 0.f);
      const float* wc = wpt + (size_t)c * 180 + obase;  // uniform, contiguous x18
      #pragma unroll
      for (int o = 0; o < 18; o++)
        acc[o] = fmaf(wc[o], v, acc[o]);
    }
  }
  #pragma unroll
  for (int o = 0; o < 18; o++)
    out[((size_t)(b * 180 + obase + o)) * PLANE_A + pp] = acc[o];
  __shared__ float rs[4][18], rq[4][18];
  int wave = tid >> 6, lane = tid & 63;
  #pragma unroll
  for (int o = 0; o < 18; o++) {
    float s = acc[o], q = acc[o] * acc[o];
    #pragma unroll
    for (int off = 32; off > 0; off >>= 1) { s += __shfl_down(s, off); q += __shfl_down(q, off); }
    if (lane == 0) { rs[wave][o] = s; rq[wave][o] = q; }
  }
  __syncthreads();
  if (tid < 18)
    psum[(obase + tid) * 72 + posblk] = rs[0][tid] + rs[1][tid] + rs[2][tid] + rs[3][tid];
  else if (tid < 36) {
    int o = tid - 18;
    psq[(obase + o) * 72 + posblk] = rq[0][o] + rq[1][o] + rq[2][o] + rq[3][o];
  }
}

// ===== final: 1x1 conv 180->9 (transposed wt) + softmax + expectation =====
__global__ __launch_bounds__(256) void k_final(const float* __restrict__ in,
    const float* __restrict__ sc, const float* __restrict__ sh,
    const float* __restrict__ wpt, float* __restrict__ out) {
  int tid = threadIdx.x;
  int t = blockIdx.x * 256 + tid;
  int b = t / PLANE_A, p = t - b * PLANE_A;
  const float* ib = in + (size_t)b * 180 * PLANE_A + p;
  float acc[9];
  #pragma unroll
  for (int o = 0; o < 9; o++) acc[o] = 0.f;
  float xn[4];
  #pragma unroll
  for (int q2 = 0; q2 < 4; q2++) xn[q2] = ib[(size_t)q2 * PLANE_A];
  #pragma unroll 1
  for (int c0 = 0; c0 < 180; c0 += 4) {
    float xv[4];
    #pragma unroll
    for (int q2 = 0; q2 < 4; q2++) xv[q2] = xn[q2];
    if (c0 + 4 < 180) {
      #pragma unroll
      for (int q2 = 0; q2 < 4; q2++) xn[q2] = ib[(size_t)(c0 + 4 + q2) * PLANE_A];
    }
    #pragma unroll
    for (int q2 = 0; q2 < 4; q2++) {
      int c = c0 + q2;
      float v = fmaxf(fmaf(xv[q2], sc[c], sh[c]), 0.f);
      const float* wc = wpt + (size_t)c * 9;        // uniform, contiguous x9
      #pragma unroll
      for (int o = 0; o < 9; o++) acc[o] = fmaf(wc[o], v, acc[o]);
    }
  }
  float m = acc[0];
  #pragma unroll
  for (int o = 1; o < 9; o++) m = fmaxf(m, acc[o]);
  float se = 0.f, num = 0.f;
  #pragma unroll
  for (int o = 0; o < 9; o++) {
    float e = expf(acc[o] - m);
    se += e;
    num += (float)(o - 4) * e;
  }
  out[t] = num / se;
}

extern "C" void kernel_launch(void* const* d_in, const int* in_sizes, int n_in,
                              void* d_out, int out_size, void* d_ws, size_t ws_size,
                              hipStream_t stream) {
  const float* x    = (const float*)d_in[0];
  const float* fw0  = (const float*)d_in[1];
  const float* fg0  = (const float*)d_in[2];
  const float* fb0  = (const float*)d_in[3];
  const float* fw   = (const float*)d_in[4];
  const float* fg   = (const float*)d_in[5];
  const float* fb   = (const float*)d_in[6];
  const float* bcw  = (const float*)d_in[7];
  const float* a0dw = (const float*)d_in[8];
  const float* a0dg = (const float*)d_in[9];
  const float* a0db = (const float*)d_in[10];
  const float* a0pw = (const float*)d_in[11];
  const float* a0pg = (const float*)d_in[12];
  const float* a0pb = (const float*)d_in[13];
  const float* amdw = (const float*)d_in[14];
  const float* amdg = (const float*)d_in[15];
  const float* amdb = (const float*)d_in[16];
  const float* ampw = (const float*)d_in[17];
  const float* ampg = (const float*)d_in[18];
  const float* ampb = (const float*)d_in[19];
  const float* ldw  = (const float*)d_in[20];
  const float* ldg  = (const float*)d_in[21];
  const float* ldb  = (const float*)d_in[22];
  const float* lpw  = (const float*)d_in[23];
  float* outp = (float*)d_out;

  float* FA    = (float*)d_ws;
  float* FB    = FA + (size_t)BB * 7 * PLANE_F;
  float* CV    = FB + (size_t)BB * 7 * PLANE_F;
  float* GA    = CV + (size_t)BB * 144 * PLANE_A;
  float* GB    = GA + (size_t)BB * 180 * PLANE_A;
  float* PSUM  = GB + (size_t)BB * 180 * PLANE_A;   // 7*972 / 180*72 both fit
  float* PSQ   = PSUM + 180 * 288;
  float* SC    = PSQ + 180 * 288;
  float* SH    = SC + 180;
  float* WT    = SH + 180;                           // 81648
  float* WPT   = WT + 81648;                         // 157140
  float* WPT_A0 = WPT;                               // [144][180]
  float* WPT_AM = WPT + 25920;                       // 4 x [180][180]
  float* WPT_L  = WPT + 25920 + 129600;              // [180][9]

  const float invNbig = 1.0f / (float)(BB * PLANE_F);
  const float invNsmall = 1.0f / (float)(BB * PLANE_A);

  // weight prep (BuildCost shuffle + pointwise transposes), one dispatch
  k_wprep<<<(238788 + 255) / 256, 256, 0, stream>>>(bcw, a0pw, ampw, lpw, WT, WPT);

  // feature extraction (SAI layout, LDS halo tiles), stats fused into conv blocks
  k_featconv0<<<NBLK_FEAT, 384, 0, stream>>>(x, fw0, FA, PSUM, PSQ);
  k_bnfinal<<<7, 256, 0, stream>>>(PSUM, PSQ, fg0, fb0, SC, SH, NBLK_FEAT, invNbig);

  float* cur = FA; float* nxt = FB;
  for (int i = 0; i < 6; i++) {
    k_featconv4<<<NBLK_FEAT, 384, 0, stream>>>(cur, fw + i * 441, SC, SH, nxt, PSUM, PSQ);
    k_bnfinal<<<7, 256, 0, stream>>>(PSUM, PSQ, fg + i * 7, fb + i * 7, SC, SH, NBLK_FEAT, invNbig);
    float* tmp = cur; cur = nxt; nxt = tmp;
  }

  // BuildCost (R6-proven structure: SGPR weights, branchless dist-1 prefetch)
  k_buildcost<<<dim3(18, 36, 2), 256, 0, stream>>>(cur, SC, SH, WT, CV);

  // aggregation: dwconv 4-row strips (SGPR weights), pwconv 18-out, fused stats
  k_dwconv<false><<<BB * 144 * 9, 256, 0, stream>>>(CV, a0dw, nullptr, nullptr, GA, PSUM, PSQ, 144);
  k_bnfinal<<<144, 256, 0, stream>>>(PSUM, PSQ, a0dg, a0db, SC, SH, 18, invNsmall);
  k_pwconv<144><<<dim3(10, 72), 256, 0, stream>>>(GA, SC, SH, WPT_A0, GB, PSUM, PSQ);
  k_bnfinal<<<180, 256, 0, stream>>>(PSUM, PSQ, a0pg, a0pb, SC, SH, 72, invNsmall);

  for (int m = 0; m < 4; m++) {
    k_dwconv<true><<<BB * 180 * 9, 256, 0, stream>>>(GB, amdw + m * 1620, SC, SH, GA, PSUM, PSQ, 180);
    k_bnfinal<<<180, 256, 0, stream>>>(PSUM, PSQ, amdg + m * 180, amdb + m * 180, SC, SH, 18, invNsmall);
    k_pwconv<180><<<dim3(10, 72), 256, 0, stream>>>(GA, SC, SH, WPT_AM + m * 32400, GB, PSUM, PSQ);
    k_bnfinal<<<180, 256, 0, stream>>>(PSUM, PSQ, ampg + m * 180, ampb + m * 180, SC, SH, 72, invNsmall);
  }

  k_dwconv<true><<<BB * 180 * 9, 256, 0, stream>>>(GB, ldw, SC, SH, GA, PSUM, PSQ, 180);
  k_bnfinal<<<180, 256, 0, stream>>>(PSUM, PSQ, ldg, ldb, SC, SH, 18, invNsmall);

  k_final<<<72, 256, 0, stream>>>(GA, SC, SH, WPT_L, outp);
}

// Round 14
// 774.556 us; speedup vs baseline: 1.0476x; 1.0476x over previous
//
#include <hip/hip_runtime.h>

#define ANG 9
#define HH 96
#define BB 2
#define PLANE_F (81*HH*HH)  // 746496 per channel (81 views x 96x96)
#define PLANE_A (HH*HH)     // 9216
#define NBLK_FEAT 1458      // BB*81*9 blocks (each: 256 threads, 4-row strips)

// ===== generic BN-final: reduce per-block partials -> scale/shift =====
__global__ __launch_bounds__(256) void k_bnfinal(const float* __restrict__ psum,
    const float* __restrict__ psq, const float* __restrict__ g, const float* __restrict__ bbias,
    float* __restrict__ sc, float* __restrict__ sh, int NB, float invN) {
  int c = blockIdx.x, tid = threadIdx.x;
  float s = 0.f, q = 0.f;
  for (int k = tid; k < NB; k += 256) { s += psum[c * NB + k]; q += psq[c * NB + k]; }
  __shared__ float ss[256], qq[256];
  ss[tid] = s; qq[tid] = q;
  __syncthreads();
  for (int st = 128; st > 0; st >>= 1) {
    if (tid < st) { ss[tid] += ss[tid + st]; qq[tid] += qq[tid + st]; }
    __syncthreads();
  }
  if (tid == 0) {
    float mean = ss[0] * invN;
    float var = fmaxf(qq[0] * invN - mean * mean, 0.f);
    float scale = g[c] / sqrtf(var + 1e-5f);
    sc[c] = scale; sh[c] = bbias[c] - mean * scale;
  }
}

// ===== weight prep: BuildCost shuffle + pointwise transposes, one dispatch =====
// wt: WT[((g*7+c)*81 + u*9+v)*16 + o]  (81648)
// wpt: [a0pw^T (144x180) | 4x ampw^T (180x180) | lpw^T (180x9)]  (157140)
__global__ __launch_bounds__(256) void k_wprep(const float* __restrict__ bcw,
    const float* __restrict__ a0pw, const float* __restrict__ ampw, const float* __restrict__ lpw,
    float* __restrict__ wt, float* __restrict__ wpt) {
  int k = blockIdx.x * 256 + threadIdx.x;
  if (k < 81648) {
    int o = k & 15; int rest = k >> 4;
    int r81 = rest % 81; int gc = rest / 81;
    int c = gc % 7, g = gc / 7;
    wt[k] = bcw[((g * 16 + o) * 7 + c) * 81 + r81];
    return;
  }
  int t = k - 81648;
  if (t < 25920) {                                   // a0pw [180][144] -> [c][o]
    int c = t / 180, o = t % 180;
    wpt[t] = a0pw[o * 144 + c];
  } else if (t < 25920 + 129600) {                   // ampw [m][180][180] -> [m][c][o]
    int t2 = t - 25920;
    int m = t2 / 32400, r = t2 % 32400;
    int c = r / 180, o = r % 180;
    wpt[t] = ampw[m * 32400 + o * 180 + c];
  } else if (t < 25920 + 129600 + 1620) {            // lpw [9][180] -> [c][o]
    int t2 = t - 25920 - 129600;
    int c = t2 / 9, o = t2 % 9;
    wpt[t] = lpw[o * 180 + c];
  }
}

// ===== feature conv0: 1->7 from raw x, branchless clamped window, fused stats =====
__global__ __launch_bounds__(256) void k_featconv0(const float* __restrict__ x,
    const float* __restrict__ w, float* __restrict__ out,
    float* __restrict__ psum, float* __restrict__ psq) {
  int blk = blockIdx.x, tid = threadIdx.x;
  int view = blk / 9, q = blk % 9;
  int b = view / 81, uv = view % 81;
  int u = uv / 9, v = uv % 9;
  int widx = q * 256 + tid;
  int j = widx % HH, i0 = (widx / HH) * 4;
  const float* bx = x + (size_t)b * PLANE_F + (u * HH) * 864 + v * HH;
  int off[6][3]; float m[6][3];
  #pragma unroll
  for (int r6 = 0; r6 < 6; r6++) {
    int ii = i0 + r6 - 1;
    float mi = ((unsigned)ii < 96u) ? 1.f : 0.f;
    int iic = min(max(ii, 0), 95);
    #pragma unroll
    for (int dx = 0; dx < 3; dx++) {
      int jj = j + dx - 1;
      float mj = ((unsigned)jj < 96u) ? 1.f : 0.f;
      int jjc = min(max(jj, 0), 95);
      off[r6][dx] = iic * 864 + jjc;
      m[r6][dx] = mi * mj;
    }
  }
  float win[6][3];
  #pragma unroll
  for (int r6 = 0; r6 < 6; r6++)
    #pragma unroll
    for (int dx = 0; dx < 3; dx++)
      win[r6][dx] = bx[off[r6][dx]] * m[r6][dx];
  float acc[4][7];
  #pragma unroll
  for (int px = 0; px < 4; px++)
    #pragma unroll
    for (int o = 0; o < 7; o++) acc[px][o] = 0.f;
  #pragma unroll
  for (int o = 0; o < 7; o++) {
    const float* wc = w + o * 9;
    #pragma unroll
    for (int ky = 0; ky < 3; ky++)
      #pragma unroll
      for (int kx = 0; kx < 3; kx++) {
        float wv = wc[ky * 3 + kx];
        #pragma unroll
        for (int px = 0; px < 4; px++)
          acc[px][o] = fmaf(win[px + ky][kx], wv, acc[px][o]);
      }
  }
  #pragma unroll
  for (int o = 0; o < 7; o++) {
    float* op = out + ((size_t)(b * 7 + o)) * PLANE_F + uv * PLANE_A + i0 * HH + j;
    #pragma unroll
    for (int px = 0; px < 4; px++) op[px * HH] = acc[px][o];
  }
  float sv[7], qv[7];
  #pragma unroll
  for (int o = 0; o < 7; o++) {
    sv[o] = acc[0][o] + acc[1][o] + acc[2][o] + acc[3][o];
    qv[o] = acc[0][o]*acc[0][o] + acc[1][o]*acc[1][o] + acc[2][o]*acc[2][o] + acc[3][o]*acc[3][o];
  }
  #pragma unroll
  for (int off2 = 32; off2 > 0; off2 >>= 1)
    #pragma unroll
    for (int o = 0; o < 7; o++) { sv[o] += __shfl_down(sv[o], off2); qv[o] += __shfl_down(qv[o], off2); }
  __shared__ float red[4][14];
  int wave = tid >> 6, lane = tid & 63;
  if (lane == 0) {
    #pragma unroll
    for (int o = 0; o < 7; o++) { red[wave][o] = sv[o]; red[wave][7 + o] = qv[o]; }
  }
  __syncthreads();
  if (tid < 14) {
    float t4 = red[0][tid] + red[1][tid] + red[2][tid] + red[3][tid];
    if (tid < 7) psum[tid * NBLK_FEAT + blk] = t4;
    else         psq[(tid - 7) * NBLK_FEAT + blk] = t4;
  }
}

// ===== feature conv: 7->7, branchless window + channel prefetch, fused stats =====
__global__ __launch_bounds__(256) void k_featconv4(const float* __restrict__ in,
    const float* __restrict__ w, const float* __restrict__ sc, const float* __restrict__ sh,
    float* __restrict__ out, float* __restrict__ psum, float* __restrict__ psq) {
  int blk = blockIdx.x, tid = threadIdx.x;
  int view = blk / 9, q = blk % 9;
  int b = view / 81, uv = view % 81;
  int widx = q * 256 + tid;
  int j = widx % HH, i0 = (widx / HH) * 4;
  int off[6][3]; float m[6][3];
  #pragma unroll
  for (int r6 = 0; r6 < 6; r6++) {
    int ii = i0 + r6 - 1;
    float mi = ((unsigned)ii < 96u) ? 1.f : 0.f;
    int iic = min(max(ii, 0), 95);
    #pragma unroll
    for (int dx = 0; dx < 3; dx++) {
      int jj = j + dx - 1;
      float mj = ((unsigned)jj < 96u) ? 1.f : 0.f;
      int jjc = min(max(jj, 0), 95);
      off[r6][dx] = iic * HH + jjc;
      m[r6][dx] = mi * mj;
    }
  }
  float acc[4][7];
  #pragma unroll
  for (int px = 0; px < 4; px++)
    #pragma unroll
    for (int o = 0; o < 7; o++) acc[px][o] = 0.f;
  const float* ipbase = in + ((size_t)(b * 7)) * PLANE_F + uv * PLANE_A;
  float pre[6][3];
  #pragma unroll
  for (int r6 = 0; r6 < 6; r6++)
    #pragma unroll
    for (int dx = 0; dx < 3; dx++)
      pre[r6][dx] = ipbase[off[r6][dx]];
  #pragma unroll 1
  for (int c = 0; c < 7; c++) {
    float s = sc[c], h2 = sh[c];
    float win[6][3];
    #pragma unroll
    for (int r6 = 0; r6 < 6; r6++)
      #pragma unroll
      for (int dx = 0; dx < 3; dx++)
        win[r6][dx] = fmaxf(fmaf(pre[r6][dx], s, h2), 0.f) * m[r6][dx];
    if (c < 6) {
      const float* ipn = ipbase + (size_t)(c + 1) * PLANE_F;
      #pragma unroll
      for (int r6 = 0; r6 < 6; r6++)
        #pragma unroll
        for (int dx = 0; dx < 3; dx++)
          pre[r6][dx] = ipn[off[r6][dx]];
    }
    #pragma unroll
    for (int o = 0; o < 7; o++) {
      const float* wc = w + (o * 7 + c) * 9;
      #pragma unroll
      for (int ky = 0; ky < 3; ky++)
        #pragma unroll
        for (int kx = 0; kx < 3; kx++) {
          float wv = wc[ky * 3 + kx];
          #pragma unroll
          for (int px = 0; px < 4; px++)
            acc[px][o] = fmaf(win[px + ky][kx], wv, acc[px][o]);
        }
    }
  }
  #pragma unroll
  for (int o = 0; o < 7; o++) {
    float* op = out + ((size_t)(b * 7 + o)) * PLANE_F + uv * PLANE_A + i0 * HH + j;
    #pragma unroll
    for (int px = 0; px < 4; px++) op[px * HH] = acc[px][o];
  }
  float sv[7], qv[7];
  #pragma unroll
  for (int o = 0; o < 7; o++) {
    sv[o] = acc[0][o] + acc[1][o] + acc[2][o] + acc[3][o];
    qv[o] = acc[0][o]*acc[0][o] + acc[1][o]*acc[1][o] + acc[2][o]*acc[2][o] + acc[3][o]*acc[3][o];
  }
  #pragma unroll
  for (int off2 = 32; off2 > 0; off2 >>= 1)
    #pragma unroll
    for (int o = 0; o < 7; o++) { sv[o] += __shfl_down(sv[o], off2); qv[o] += __shfl_down(qv[o], off2); }
  __shared__ float red[4][14];
  int wave = tid >> 6, lane = tid & 63;
  if (lane == 0) {
    #pragma unroll
    for (int o = 0; o < 7; o++) { red[wave][o] = sv[o]; red[wave][7 + o] = qv[o]; }
  }
  __syncthreads();
  if (tid < 14) {
    float t4 = red[0][tid] + red[1][tid] + red[2][tid] + red[3][tid];
    if (tid < 7) psum[tid * NBLK_FEAT + blk] = t4;
    else         psq[(tid - 7) * NBLK_FEAT + blk] = t4;
  }
}

// ===== BuildCost helper: branchless clamped 9-tap load (R6-proven) =====
__device__ __forceinline__ void bc_load(const float* __restrict__ F, int b, int c, int u,
    int d, int i, int j, float* raw, float* msk) {
  const float* Fc = F + ((size_t)(b * 7 + c)) * PLANE_F + (u * 9) * PLANE_A;
  int ii = i + d * (4 - u);
  float mi = ((unsigned)ii < 96u) ? 1.f : 0.f;
  int iic = min(max(ii, 0), 95);
  const float* Frow = Fc + iic * HH;
  #pragma unroll
  for (int v = 0; v < 9; v++) {
    int jj = j + d * (4 - v);
    float mj = ((unsigned)jj < 96u) ? 1.f : 0.f;
    int jjc = min(max(jj, 0), 95);
    raw[v] = Frow[v * PLANE_A + jjc];
    msk[v] = mi * mj;
  }
}

// ===== BuildCost: full 16-o per block, SGPR weights, dist-1 prefetch =====
// grid (9, 36, 2): x = g, y = pos block, z = b. Each bc_load feeds 16 FMAs/v.
__global__ __launch_bounds__(256) void k_buildcost(const float* __restrict__ F,
    const float* __restrict__ sc, const float* __restrict__ sh,
    const float* __restrict__ wt, float* __restrict__ cv) {
  int g = blockIdx.x, b = blockIdx.z, tid = threadIdx.x;
  int d = g - 4;
  bool flip = d > 0;
  int p = blockIdx.y * 256 + tid;
  int i = p / HH, j = p % HH;
  float acc[16];
  #pragma unroll
  for (int o = 0; o < 16; o++) acc[o] = 0.f;
  float raw[9], msk[9];
  bc_load(F, b, 0, 0, d, i, j, raw, msk);
  #pragma unroll 1
  for (int cu = 0; cu < 63; cu++) {
    int c = cu / 9, u = cu - c * 9;
    float cr[9], cm[9];
    #pragma unroll
    for (int v = 0; v < 9; v++) { cr[v] = raw[v]; cm[v] = msk[v]; }
    if (cu + 1 < 63) {
      int cn = (cu + 1) / 9, un = (cu + 1) - cn * 9;
      bc_load(F, b, cn, un, d, i, j, raw, msk);
    }
    float s = sc[c], h2 = sh[c];
    int uw = flip ? 8 - u : u;
    const float* wbase = wt + ((size_t)((g * 7 + c) * 81 + uw * 9)) * 16;
    #pragma unroll
    for (int v = 0; v < 9; v++) {
      float a = fmaxf(fmaf(cr[v], s, h2), 0.f) * cm[v];
      int vw = flip ? 8 - v : v;
      const float* wp = wbase + vw * 16;            // uniform -> s_load
      #pragma unroll
      for (int o = 0; o < 16; o++) acc[o] = fmaf(wp[o], a, acc[o]);
    }
  }
  size_t cvb = ((size_t)(b * 144 + g * 16)) * PLANE_A + p;
  #pragma unroll
  for (int o = 0; o < 16; o++) cv[cvb + o * PLANE_A] = acc[o];
}

// ===== depthwise 3x3: 4-row strips, block-uniform channel (SGPR weights) =====
// grid: BB*C*9 blocks; blk = (b*C + c)*9 + q. Stats: psum[c*18 + b*9 + q].
template<bool AFF>
__global__ __launch_bounds__(256) void k_dwconv(const float* __restrict__ in,
    const float* __restrict__ w, const float* __restrict__ isc, const float* __restrict__ ish,
    float* __restrict__ out, float* __restrict__ psum, float* __restrict__ psq, int C) {
  int blk = blockIdx.x, tid = threadIdx.x;
  int q = blk % 9; int rr = blk / 9; int c = rr % C; int b = rr / C;
  int widx = q * 256 + tid;
  int j = widx % HH, i0 = (widx / HH) * 4;
  float s  = AFF ? isc[c] : 1.f;                    // uniform -> s_load
  float h2 = AFF ? ish[c] : 0.f;
  const float* wc = w + c * 9;                      // uniform -> s_load
  const float* ip = in + ((size_t)(b * C + c)) * PLANE_A;
  int off[6][3]; float m[6][3];
  #pragma unroll
  for (int r6 = 0; r6 < 6; r6++) {
    int ii = i0 + r6 - 1;
    float mi = ((unsigned)ii < 96u) ? 1.f : 0.f;
    int iic = min(max(ii, 0), 95);
    #pragma unroll
    for (int dx = 0; dx < 3; dx++) {
      int jj = j + dx - 1;
      float mj = ((unsigned)jj < 96u) ? 1.f : 0.f;
      int jjc = min(max(jj, 0), 95);
      off[r6][dx] = iic * HH + jjc;
      m[r6][dx] = mi * mj;
    }
  }
  float win[6][3];
  #pragma unroll
  for (int r6 = 0; r6 < 6; r6++)
    #pragma unroll
    for (int dx = 0; dx < 3; dx++) {
      float vv = ip[off[r6][dx]];
      if (AFF) vv = fmaxf(fmaf(vv, s, h2), 0.f);
      win[r6][dx] = vv * m[r6][dx];
    }
  float acc[4];
  #pragma unroll
  for (int px = 0; px < 4; px++) acc[px] = 0.f;
  #pragma unroll
  for (int ky = 0; ky < 3; ky++)
    #pragma unroll
    for (int kx = 0; kx < 3; kx++) {
      float wv = wc[ky * 3 + kx];
      #pragma unroll
      for (int px = 0; px < 4; px++)
        acc[px] = fmaf(win[px + ky][kx], wv, acc[px]);
    }
  float* op = out + ((size_t)(b * C + c)) * PLANE_A + i0 * HH + j;
  #pragma unroll
  for (int px = 0; px < 4; px++) op[px * HH] = acc[px];
  float sv = acc[0] + acc[1] + acc[2] + acc[3];
  float qv = acc[0]*acc[0] + acc[1]*acc[1] + acc[2]*acc[2] + acc[3]*acc[3];
  #pragma unroll
  for (int off2 = 32; off2 > 0; off2 >>= 1) { sv += __shfl_down(sv, off2); qv += __shfl_down(qv, off2); }
  __shared__ float red[4][2];
  int wave = tid >> 6, lane = tid & 63;
  if (lane == 0) { red[wave][0] = sv; red[wave][1] = qv; }
  __syncthreads();
  if (tid == 0) {
    float S = red[0][0] + red[1][0] + red[2][0] + red[3][0];
    float Q = red[0][1] + red[1][1] + red[2][1] + red[3][1];
    psum[c * 18 + b * 9 + q] = S;
    psq [c * 18 + b * 9 + q] = Q;
  }
}

// ===== pointwise conv: 18 out/thread, transposed weights (contiguous s_load) =====
// grid (10, 72): x = output group (18 outputs), y = position block
template<int K>
__global__ __launch_bounds__(256) void k_pwconv(const float* __restrict__ in,
    const float* __restrict__ sc, const float* __restrict__ sh,
    const float* __restrict__ wpt, float* __restrict__ out,
    float* __restrict__ psum, float* __restrict__ psq) {
  int tid = threadIdx.x;
  int posblk = blockIdx.y;
  int p = posblk * 256 + tid;
  int b = p / PLANE_A, pp = p - b * PLANE_A;
  int obase = blockIdx.x * 18;
  float acc[18];
  #pragma unroll
  for (int o = 0; o < 18; o++) acc[o] = 0.f;
  const float* ib = in + (size_t)b * K * PLANE_A + pp;
  float xn[4];
  #pragma unroll
  for (int q2 = 0; q2 < 4; q2++) xn[q2] = ib[(size_t)q2 * PLANE_A];
  #pragma unroll 1
  for (int c0 = 0; c0 < K; c0 += 4) {
    float xv[4];
    #pragma unroll
    for (int q2 = 0; q2 < 4; q2++) xv[q2] = xn[q2];
    if (c0 + 4 < K) {
      #pragma unroll
      for (int q2 = 0; q2 < 4; q2++) xn[q2] = ib[(size_t)(c0 + 4 + q2) * PLANE_A];
    }
    #pragma unroll
    for (int q2 = 0; q2 < 4; q2++) {
      int c = c0 + q2;
      float v = fmaxf(fmaf(xv[q2], sc[c], sh[c]), 0.f);
      const float* wc = wpt + (size_t)c * 180 + obase;  // uniform, contiguous x18
      #pragma unroll
      for (int o = 0; o < 18; o++)
        acc[o] = fmaf(wc[o], v, acc[o]);
    }
  }
  #pragma unroll
  for (int o = 0; o < 18; o++)
    out[((size_t)(b * 180 + obase + o)) * PLANE_A + pp] = acc[o];
  __shared__ float rs[4][18], rq[4][18];
  int wave = tid >> 6, lane = tid & 63;
  #pragma unroll
  for (int o = 0; o < 18; o++) {
    float s = acc[o], q = acc[o] * acc[o];
    #pragma unroll
    for (int off = 32; off > 0; off >>= 1) { s += __shfl_down(s, off); q += __shfl_down(q, off); }
    if (lane == 0) { rs[wave][o] = s; rq[wave][o] = q; }
  }
  __syncthreads();
  if (tid < 18)
    psum[(obase + tid) * 72 + posblk] = rs[0][tid] + rs[1][tid] + rs[2][tid] + rs[3][tid];
  else if (tid < 36) {
    int o = tid - 18;
    psq[(obase + o) * 72 + posblk] = rq[0][o] + rq[1][o] + rq[2][o] + rq[3][o];
  }
}

// ===== final: 1x1 conv 180->9 (transposed wt) + softmax + expectation =====
__global__ __launch_bounds__(256) void k_final(const float* __restrict__ in,
    const float* __restrict__ sc, const float* __restrict__ sh,
    const float* __restrict__ wpt, float* __restrict__ out) {
  int tid = threadIdx.x;
  int t = blockIdx.x * 256 + tid;
  int b = t / PLANE_A, p = t - b * PLANE_A;
  const float* ib = in + (size_t)b * 180 * PLANE_A + p;
  float acc[9];
  #pragma unroll
  for (int o = 0; o < 9; o++) acc[o] = 0.f;
  float xn[4];
  #pragma unroll
  for (int q2 = 0; q2 < 4; q2++) xn[q2] = ib[(size_t)q2 * PLANE_A];
  #pragma unroll 1
  for (int c0 = 0; c0 < 180; c0 += 4) {
    float xv[4];
    #pragma unroll
    for (int q2 = 0; q2 < 4; q2++) xv[q2] = xn[q2];
    if (c0 + 4 < 180) {
      #pragma unroll
      for (int q2 = 0; q2 < 4; q2++) xn[q2] = ib[(size_t)(c0 + 4 + q2) * PLANE_A];
    }
    #pragma unroll
    for (int q2 = 0; q2 < 4; q2++) {
      int c = c0 + q2;
      float v = fmaxf(fmaf(xv[q2], sc[c], sh[c]), 0.f);
      const float* wc = wpt + (size_t)c * 9;        // uniform, contiguous x9
      #pragma unroll
      for (int o = 0; o < 9; o++) acc[o] = fmaf(wc[o], v, acc[o]);
    }
  }
  float m = acc[0];
  #pragma unroll
  for (int o = 1; o < 9; o++) m = fmaxf(m, acc[o]);
  float se = 0.f, num = 0.f;
  #pragma unroll
  for (int o = 0; o < 9; o++) {
    float e = expf(acc[o] - m);
    se += e;
    num += (float)(o - 4) * e;
  }
  out[t] = num / se;
}

extern "C" void kernel_launch(void* const* d_in, const int* in_sizes, int n_in,
                              void* d_out, int out_size, void* d_ws, size_t ws_size,
                              hipStream_t stream) {
  const float* x    = (const float*)d_in[0];
  const float* fw0  = (const float*)d_in[1];
  const float* fg0  = (const float*)d_in[2];
  const float* fb0  = (const float*)d_in[3];
  const float* fw   = (const float*)d_in[4];
  const float* fg   = (const float*)d_in[5];
  const float* fb   = (const float*)d_in[6];
  const float* bcw  = (const float*)d_in[7];
  const float* a0dw = (const float*)d_in[8];
  const float* a0dg = (const float*)d_in[9];
  const float* a0db = (const float*)d_in[10];
  const float* a0pw = (const float*)d_in[11];
  const float* a0pg = (const float*)d_in[12];
  const float* a0pb = (const float*)d_in[13];
  const float* amdw = (const float*)d_in[14];
  const float* amdg = (const float*)d_in[15];
  const float* amdb = (const float*)d_in[16];
  const float* ampw = (const float*)d_in[17];
  const float* ampg = (const float*)d_in[18];
  const float* ampb = (const float*)d_in[19];
  const float* ldw  = (const float*)d_in[20];
  const float* ldg  = (const float*)d_in[21];
  const float* ldb  = (const float*)d_in[22];
  const float* lpw  = (const float*)d_in[23];
  float* outp = (float*)d_out;

  float* FA    = (float*)d_ws;
  float* FB    = FA + (size_t)BB * 7 * PLANE_F;
  float* CV    = FB + (size_t)BB * 7 * PLANE_F;
  float* GA    = CV + (size_t)BB * 144 * PLANE_A;
  float* GB    = GA + (size_t)BB * 180 * PLANE_A;
  float* PSUM  = GB + (size_t)BB * 180 * PLANE_A;   // 7*1458 / 180*72 both fit
  float* PSQ   = PSUM + 180 * 288;
  float* SC    = PSQ + 180 * 288;
  float* SH    = SC + 180;
  float* WT    = SH + 180;                           // 81648
  float* WPT   = WT + 81648;                         // 157140
  float* WPT_A0 = WPT;                               // [144][180]
  float* WPT_AM = WPT + 25920;                       // 4 x [180][180]
  float* WPT_L  = WPT + 25920 + 129600;              // [180][9]

  const float invNbig = 1.0f / (float)(BB * PLANE_F);
  const float invNsmall = 1.0f / (float)(BB * PLANE_A);

  // weight prep (BuildCost shuffle + pointwise transposes), one dispatch
  k_wprep<<<(238788 + 255) / 256, 256, 0, stream>>>(bcw, a0pw, ampw, lpw, WT, WPT);

  // feature extraction (SAI layout, fp32), stats fused into conv blocks
  k_featconv0<<<NBLK_FEAT, 256, 0, stream>>>(x, fw0, FA, PSUM, PSQ);
  k_bnfinal<<<7, 256, 0, stream>>>(PSUM, PSQ, fg0, fb0, SC, SH, NBLK_FEAT, invNbig);

  float* cur = FA; float* nxt = FB;
  for (int i = 0; i < 6; i++) {
    k_featconv4<<<NBLK_FEAT, 256, 0, stream>>>(cur, fw + i * 441, SC, SH, nxt, PSUM, PSQ);
    k_bnfinal<<<7, 256, 0, stream>>>(PSUM, PSQ, fg + i * 7, fb + i * 7, SC, SH, NBLK_FEAT, invNbig);
    float* tmp = cur; cur = nxt; nxt = tmp;
  }

  // BuildCost (16 outputs/block, SGPR weights, branchless dist-1 prefetch)
  k_buildcost<<<dim3(9, 36, 2), 256, 0, stream>>>(cur, SC, SH, WT, CV);

  // aggregation: dwconv 4-row strips (SGPR weights), pwconv 18-out, fused stats
  k_dwconv<false><<<BB * 144 * 9, 256, 0, stream>>>(CV, a0dw, nullptr, nullptr, GA, PSUM, PSQ, 144);
  k_bnfinal<<<144, 256, 0, stream>>>(PSUM, PSQ, a0dg, a0db, SC, SH, 18, invNsmall);
  k_pwconv<144><<<dim3(10, 72), 256, 0, stream>>>(GA, SC, SH, WPT_A0, GB, PSUM, PSQ);
  k_bnfinal<<<180, 256, 0, stream>>>(PSUM, PSQ, a0pg, a0pb, SC, SH, 72, invNsmall);

  for (int m = 0; m < 4; m++) {
    k_dwconv<true><<<BB * 180 * 9, 256, 0, stream>>>(GB, amdw + m * 1620, SC, SH, GA, PSUM, PSQ, 180);
    k_bnfinal<<<180, 256, 0, stream>>>(PSUM, PSQ, amdg + m * 180, amdb + m * 180, SC, SH, 18, invNsmall);
    k_pwconv<180><<<dim3(10, 72), 256, 0, stream>>>(GA, SC, SH, WPT_AM + m * 32400, GB, PSUM, PSQ);
    k_bnfinal<<<180, 256, 0, stream>>>(PSUM, PSQ, ampg + m * 180, ampb + m * 180, SC, SH, 72, invNsmall);
  }

  k_dwconv<true><<<BB * 180 * 9, 256, 0, stream>>>(GB, ldw, SC, SH, GA, PSUM, PSQ, 180);
  k_bnfinal<<<180, 256, 0, stream>>>(PSUM, PSQ, ldg, ldb, SC, SH, 18, invNsmall);

  k_final<<<72, 256, 0, stream>>>(GA, SC, SH, WPT_L, outp);
}

// Round 15
// 765.900 us; speedup vs baseline: 1.0594x; 1.0113x over previous
//
#include <hip/hip_runtime.h>

#define ANG 9
#define HH 96
#define BB 2
#define PLANE_F (81*HH*HH)  // 746496 per channel (81 views x 96x96)
#define PLANE_A (HH*HH)     // 9216
#define NBLK_FEAT 1458      // BB*81*9 blocks (each: 256 threads, 4-row strips)

typedef float f4 __attribute__((ext_vector_type(4), aligned(4)));  // 4B-aligned vector load

// Select 3-window raw values (cols j-1,j,j+1) from one f4 row load at base.
// base = j0 ? 0 : (j95 ? 92 : j-1). Edge lanes get garbage in masked slots.
__device__ __forceinline__ void row3sel(const float* rp, int base, bool j0, bool j95,
                                        float& w0, float& w1, float& w2) {
  f4 v = *(const f4*)(rp + base);
  w0 = j95 ? v.z : v.x;
  w1 = j0 ? v.x : (j95 ? v.w : v.y);
  w2 = j0 ? v.y : v.z;
}

// ===== generic BN-final: reduce per-block partials -> scale/shift =====
__global__ __launch_bounds__(256) void k_bnfinal(const float* __restrict__ psum,
    const float* __restrict__ psq, const float* __restrict__ g, const float* __restrict__ bbias,
    float* __restrict__ sc, float* __restrict__ sh, int NB, float invN) {
  int c = blockIdx.x, tid = threadIdx.x;
  float s = 0.f, q = 0.f;
  for (int k = tid; k < NB; k += 256) { s += psum[c * NB + k]; q += psq[c * NB + k]; }
  __shared__ float ss[256], qq[256];
  ss[tid] = s; qq[tid] = q;
  __syncthreads();
  for (int st = 128; st > 0; st >>= 1) {
    if (tid < st) { ss[tid] += ss[tid + st]; qq[tid] += qq[tid + st]; }
    __syncthreads();
  }
  if (tid == 0) {
    float mean = ss[0] * invN;
    float var = fmaxf(qq[0] * invN - mean * mean, 0.f);
    float scale = g[c] / sqrtf(var + 1e-5f);
    sc[c] = scale; sh[c] = bbias[c] - mean * scale;
  }
}

// ===== weight prep: BuildCost shuffle + pointwise transposes, one dispatch =====
__global__ __launch_bounds__(256) void k_wprep(const float* __restrict__ bcw,
    const float* __restrict__ a0pw, const float* __restrict__ ampw, const float* __restrict__ lpw,
    float* __restrict__ wt, float* __restrict__ wpt) {
  int k = blockIdx.x * 256 + threadIdx.x;
  if (k < 81648) {
    int o = k & 15; int rest = k >> 4;
    int r81 = rest % 81; int gc = rest / 81;
    int c = gc % 7, g = gc / 7;
    wt[k] = bcw[((g * 16 + o) * 7 + c) * 81 + r81];
    return;
  }
  int t = k - 81648;
  if (t < 25920) {                                   // a0pw [180][144] -> [c][o]
    int c = t / 180, o = t % 180;
    wpt[t] = a0pw[o * 144 + c];
  } else if (t < 25920 + 129600) {                   // ampw [m][180][180] -> [m][c][o]
    int t2 = t - 25920;
    int m = t2 / 32400, r = t2 % 32400;
    int c = r / 180, o = r % 180;
    wpt[t] = ampw[m * 32400 + o * 180 + c];
  } else if (t < 25920 + 129600 + 1620) {            // lpw [9][180] -> [c][o]
    int t2 = t - 25920 - 129600;
    int c = t2 / 9, o = t2 % 9;
    wpt[t] = lpw[o * 180 + c];
  }
}

// ===== feature conv0: 1->7 from raw x, vector row loads, fused stats =====
__global__ __launch_bounds__(256) void k_featconv0(const float* __restrict__ x,
    const float* __restrict__ w, float* __restrict__ out,
    float* __restrict__ psum, float* __restrict__ psq) {
  int blk = blockIdx.x, tid = threadIdx.x;
  int view = blk / 9, q = blk % 9;
  int b = view / 81, uv = view % 81;
  int u = uv / 9, v = uv % 9;
  int widx = q * 256 + tid;
  int j = widx % HH, i0 = (widx / HH) * 4;
  bool j0 = (j == 0), j95 = (j == 95);
  int base = j0 ? 0 : (j95 ? 92 : j - 1);
  float me0 = j0 ? 0.f : 1.f, me2 = j95 ? 0.f : 1.f;
  const float* bx = x + (size_t)b * PLANE_F + (u * HH) * 864 + v * HH;
  float win[6][3];
  #pragma unroll
  for (int r6 = 0; r6 < 6; r6++) {
    int ii = i0 + r6 - 1;
    float mi = ((unsigned)ii < 96u) ? 1.f : 0.f;
    int iic = min(max(ii, 0), 95);
    float w0, w1, w2;
    row3sel(bx + iic * 864, base, j0, j95, w0, w1, w2);
    win[r6][0] = w0 * (mi * me0);
    win[r6][1] = w1 * mi;
    win[r6][2] = w2 * (mi * me2);
  }
  float acc[4][7];
  #pragma unroll
  for (int px = 0; px < 4; px++)
    #pragma unroll
    for (int o = 0; o < 7; o++) acc[px][o] = 0.f;
  #pragma unroll
  for (int o = 0; o < 7; o++) {
    const float* wc = w + o * 9;
    #pragma unroll
    for (int ky = 0; ky < 3; ky++)
      #pragma unroll
      for (int kx = 0; kx < 3; kx++) {
        float wv = wc[ky * 3 + kx];
        #pragma unroll
        for (int px = 0; px < 4; px++)
          acc[px][o] = fmaf(win[px + ky][kx], wv, acc[px][o]);
      }
  }
  #pragma unroll
  for (int o = 0; o < 7; o++) {
    float* op = out + ((size_t)(b * 7 + o)) * PLANE_F + uv * PLANE_A + i0 * HH + j;
    #pragma unroll
    for (int px = 0; px < 4; px++) op[px * HH] = acc[px][o];
  }
  float sv[7], qv[7];
  #pragma unroll
  for (int o = 0; o < 7; o++) {
    sv[o] = acc[0][o] + acc[1][o] + acc[2][o] + acc[3][o];
    qv[o] = acc[0][o]*acc[0][o] + acc[1][o]*acc[1][o] + acc[2][o]*acc[2][o] + acc[3][o]*acc[3][o];
  }
  #pragma unroll
  for (int off2 = 32; off2 > 0; off2 >>= 1)
    #pragma unroll
    for (int o = 0; o < 7; o++) { sv[o] += __shfl_down(sv[o], off2); qv[o] += __shfl_down(qv[o], off2); }
  __shared__ float red[4][14];
  int wave = tid >> 6, lane = tid & 63;
  if (lane == 0) {
    #pragma unroll
    for (int o = 0; o < 7; o++) { red[wave][o] = sv[o]; red[wave][7 + o] = qv[o]; }
  }
  __syncthreads();
  if (tid < 14) {
    float t4 = red[0][tid] + red[1][tid] + red[2][tid] + red[3][tid];
    if (tid < 7) psum[tid * NBLK_FEAT + blk] = t4;
    else         psq[(tid - 7) * NBLK_FEAT + blk] = t4;
  }
}

// ===== feature conv: 7->7, vector row loads + channel prefetch, fused stats =====
__global__ __launch_bounds__(256) void k_featconv4(const float* __restrict__ in,
    const float* __restrict__ w, const float* __restrict__ sc, const float* __restrict__ sh,
    float* __restrict__ out, float* __restrict__ psum, float* __restrict__ psq) {
  int blk = blockIdx.x, tid = threadIdx.x;
  int view = blk / 9, q = blk % 9;
  int b = view / 81, uv = view % 81;
  int widx = q * 256 + tid;
  int j = widx % HH, i0 = (widx / HH) * 4;
  bool j0 = (j == 0), j95 = (j == 95);
  int base = j0 ? 0 : (j95 ? 92 : j - 1);
  float me0 = j0 ? 0.f : 1.f, me2 = j95 ? 0.f : 1.f;
  float mrow[6]; int roff[6];
  #pragma unroll
  for (int r6 = 0; r6 < 6; r6++) {
    int ii = i0 + r6 - 1;
    mrow[r6] = ((unsigned)ii < 96u) ? 1.f : 0.f;
    roff[r6] = min(max(ii, 0), 95) * HH + base;
  }
  float acc[4][7];
  #pragma unroll
  for (int px = 0; px < 4; px++)
    #pragma unroll
    for (int o = 0; o < 7; o++) acc[px][o] = 0.f;
  const float* ipbase = in + ((size_t)(b * 7)) * PLANE_F + uv * PLANE_A;
  float pre[6][3];
  #pragma unroll
  for (int r6 = 0; r6 < 6; r6++)
    row3sel(ipbase + roff[r6], 0, j0, j95, pre[r6][0], pre[r6][1], pre[r6][2]);
  #pragma unroll 1
  for (int c = 0; c < 7; c++) {
    float s = sc[c], h2 = sh[c];
    float win[6][3];
    #pragma unroll
    for (int r6 = 0; r6 < 6; r6++) {
      win[r6][0] = fmaxf(fmaf(pre[r6][0], s, h2), 0.f) * (mrow[r6] * me0);
      win[r6][1] = fmaxf(fmaf(pre[r6][1], s, h2), 0.f) * mrow[r6];
      win[r6][2] = fmaxf(fmaf(pre[r6][2], s, h2), 0.f) * (mrow[r6] * me2);
    }
    if (c < 6) {
      const float* ipn = ipbase + (size_t)(c + 1) * PLANE_F;
      #pragma unroll
      for (int r6 = 0; r6 < 6; r6++)
        row3sel(ipn + roff[r6], 0, j0, j95, pre[r6][0], pre[r6][1], pre[r6][2]);
    }
    #pragma unroll
    for (int o = 0; o < 7; o++) {
      const float* wc = w + (o * 7 + c) * 9;
      #pragma unroll
      for (int ky = 0; ky < 3; ky++)
        #pragma unroll
        for (int kx = 0; kx < 3; kx++) {
          float wv = wc[ky * 3 + kx];
          #pragma unroll
          for (int px = 0; px < 4; px++)
            acc[px][o] = fmaf(win[px + ky][kx], wv, acc[px][o]);
        }
    }
  }
  #pragma unroll
  for (int o = 0; o < 7; o++) {
    float* op = out + ((size_t)(b * 7 + o)) * PLANE_F + uv * PLANE_A + i0 * HH + j;
    #pragma unroll
    for (int px = 0; px < 4; px++) op[px * HH] = acc[px][o];
  }
  float sv[7], qv[7];
  #pragma unroll
  for (int o = 0; o < 7; o++) {
    sv[o] = acc[0][o] + acc[1][o] + acc[2][o] + acc[3][o];
    qv[o] = acc[0][o]*acc[0][o] + acc[1][o]*acc[1][o] + acc[2][o]*acc[2][o] + acc[3][o]*acc[3][o];
  }
  #pragma unroll
  for (int off2 = 32; off2 > 0; off2 >>= 1)
    #pragma unroll
    for (int o = 0; o < 7; o++) { sv[o] += __shfl_down(sv[o], off2); qv[o] += __shfl_down(qv[o], off2); }
  __shared__ float red[4][14];
  int wave = tid >> 6, lane = tid & 63;
  if (lane == 0) {
    #pragma unroll
    for (int o = 0; o < 7; o++) { red[wave][o] = sv[o]; red[wave][7 + o] = qv[o]; }
  }
  __syncthreads();
  if (tid < 14) {
    float t4 = red[0][tid] + red[1][tid] + red[2][tid] + red[3][tid];
    if (tid < 7) psum[tid * NBLK_FEAT + blk] = t4;
    else         psq[(tid - 7) * NBLK_FEAT + blk] = t4;
  }
}

// ===== BuildCost helper: branchless clamped 9-tap load (R6-proven) =====
__device__ __forceinline__ void bc_load(const float* __restrict__ F, int b, int c, int u,
    int d, int i, int j, float* raw, float* msk) {
  const float* Fc = F + ((size_t)(b * 7 + c)) * PLANE_F + (u * 9) * PLANE_A;
  int ii = i + d * (4 - u);
  float mi = ((unsigned)ii < 96u) ? 1.f : 0.f;
  int iic = min(max(ii, 0), 95);
  const float* Frow = Fc + iic * HH;
  #pragma unroll
  for (int v = 0; v < 9; v++) {
    int jj = j + d * (4 - v);
    float mj = ((unsigned)jj < 96u) ? 1.f : 0.f;
    int jjc = min(max(jj, 0), 95);
    raw[v] = Frow[v * PLANE_A + jjc];
    msk[v] = mi * mj;
  }
}

// ===== BuildCost: full 16-o per block, SGPR weights, dist-1 prefetch (R14) =====
// grid (9, 36, 2): x = g, y = pos block, z = b. Each bc_load feeds 16 FMAs/v.
__global__ __launch_bounds__(256) void k_buildcost(const float* __restrict__ F,
    const float* __restrict__ sc, const float* __restrict__ sh,
    const float* __restrict__ wt, float* __restrict__ cv) {
  int g = blockIdx.x, b = blockIdx.z, tid = threadIdx.x;
  int d = g - 4;
  bool flip = d > 0;
  int p = blockIdx.y * 256 + tid;
  int i = p / HH, j = p % HH;
  float acc[16];
  #pragma unroll
  for (int o = 0; o < 16; o++) acc[o] = 0.f;
  float raw[9], msk[9];
  bc_load(F, b, 0, 0, d, i, j, raw, msk);
  #pragma unroll 1
  for (int cu = 0; cu < 63; cu++) {
    int c = cu / 9, u = cu - c * 9;
    float cr[9], cm[9];
    #pragma unroll
    for (int v = 0; v < 9; v++) { cr[v] = raw[v]; cm[v] = msk[v]; }
    if (cu + 1 < 63) {
      int cn = (cu + 1) / 9, un = (cu + 1) - cn * 9;
      bc_load(F, b, cn, un, d, i, j, raw, msk);
    }
    float s = sc[c], h2 = sh[c];
    int uw = flip ? 8 - u : u;
    const float* wbase = wt + ((size_t)((g * 7 + c) * 81 + uw * 9)) * 16;
    #pragma unroll
    for (int v = 0; v < 9; v++) {
      float a = fmaxf(fmaf(cr[v], s, h2), 0.f) * cm[v];
      int vw = flip ? 8 - v : v;
      const float* wp = wbase + vw * 16;            // uniform -> s_load
      #pragma unroll
      for (int o = 0; o < 16; o++) acc[o] = fmaf(wp[o], a, acc[o]);
    }
  }
  size_t cvb = ((size_t)(b * 144 + g * 16)) * PLANE_A + p;
  #pragma unroll
  for (int o = 0; o < 16; o++) cv[cvb + o * PLANE_A] = acc[o];
}

// ===== depthwise 3x3: 4-row strips, SGPR weights, vector row loads =====
// grid: BB*C*9 blocks; blk = (b*C + c)*9 + q. Stats: psum[c*18 + b*9 + q].
template<bool AFF>
__global__ __launch_bounds__(256) void k_dwconv(const float* __restrict__ in,
    const float* __restrict__ w, const float* __restrict__ isc, const float* __restrict__ ish,
    float* __restrict__ out, float* __restrict__ psum, float* __restrict__ psq, int C) {
  int blk = blockIdx.x, tid = threadIdx.x;
  int q = blk % 9; int rr = blk / 9; int c = rr % C; int b = rr / C;
  int widx = q * 256 + tid;
  int j = widx % HH, i0 = (widx / HH) * 4;
  bool j0 = (j == 0), j95 = (j == 95);
  int base = j0 ? 0 : (j95 ? 92 : j - 1);
  float me0 = j0 ? 0.f : 1.f, me2 = j95 ? 0.f : 1.f;
  float s  = AFF ? isc[c] : 1.f;                    // uniform -> s_load
  float h2 = AFF ? ish[c] : 0.f;
  const float* wc = w + c * 9;                      // uniform -> s_load
  const float* ip = in + ((size_t)(b * C + c)) * PLANE_A;
  float win[6][3];
  #pragma unroll
  for (int r6 = 0; r6 < 6; r6++) {
    int ii = i0 + r6 - 1;
    float mi = ((unsigned)ii < 96u) ? 1.f : 0.f;
    int iic = min(max(ii, 0), 95);
    float w0, w1, w2;
    row3sel(ip + iic * HH, base, j0, j95, w0, w1, w2);
    if (AFF) {
      w0 = fmaxf(fmaf(w0, s, h2), 0.f);
      w1 = fmaxf(fmaf(w1, s, h2), 0.f);
      w2 = fmaxf(fmaf(w2, s, h2), 0.f);
    }
    win[r6][0] = w0 * (mi * me0);
    win[r6][1] = w1 * mi;
    win[r6][2] = w2 * (mi * me2);
  }
  float acc[4];
  #pragma unroll
  for (int px = 0; px < 4; px++) acc[px] = 0.f;
  #pragma unroll
  for (int ky = 0; ky < 3; ky++)
    #pragma unroll
    for (int kx = 0; kx < 3; kx++) {
      float wv = wc[ky * 3 + kx];
      #pragma unroll
      for (int px = 0; px < 4; px++)
        acc[px] = fmaf(win[px + ky][kx], wv, acc[px]);
    }
  float* op = out + ((size_t)(b * C + c)) * PLANE_A + i0 * HH + j;
  #pragma unroll
  for (int px = 0; px < 4; px++) op[px * HH] = acc[px];
  float sv = acc[0] + acc[1] + acc[2] + acc[3];
  float qv = acc[0]*acc[0] + acc[1]*acc[1] + acc[2]*acc[2] + acc[3]*acc[3];
  #pragma unroll
  for (int off2 = 32; off2 > 0; off2 >>= 1) { sv += __shfl_down(sv, off2); qv += __shfl_down(qv, off2); }
  __shared__ float red[4][2];
  int wave = tid >> 6, lane = tid & 63;
  if (lane == 0) { red[wave][0] = sv; red[wave][1] = qv; }
  __syncthreads();
  if (tid == 0) {
    float S = red[0][0] + red[1][0] + red[2][0] + red[3][0];
    float Q = red[0][1] + red[1][1] + red[2][1] + red[3][1];
    psum[c * 18 + b * 9 + q] = S;
    psq [c * 18 + b * 9 + q] = Q;
  }
}

// ===== pointwise conv: 18 out/thread, transposed weights (contiguous s_load) =====
// grid (10, 72): x = output group (18 outputs), y = position block
template<int K>
__global__ __launch_bounds__(256) void k_pwconv(const float* __restrict__ in,
    const float* __restrict__ sc, const float* __restrict__ sh,
    const float* __restrict__ wpt, float* __restrict__ out,
    float* __restrict__ psum, float* __restrict__ psq) {
  int tid = threadIdx.x;
  int posblk = blockIdx.y;
  int p = posblk * 256 + tid;
  int b = p / PLANE_A, pp = p - b * PLANE_A;
  int obase = blockIdx.x * 18;
  float acc[18];
  #pragma unroll
  for (int o = 0; o < 18; o++) acc[o] = 0.f;
  const float* ib = in + (size_t)b * K * PLANE_A + pp;
  float xn[4];
  #pragma unroll
  for (int q2 = 0; q2 < 4; q2++) xn[q2] = ib[(size_t)q2 * PLANE_A];
  #pragma unroll 1
  for (int c0 = 0; c0 < K; c0 += 4) {
    float xv[4];
    #pragma unroll
    for (int q2 = 0; q2 < 4; q2++) xv[q2] = xn[q2];
    if (c0 + 4 < K) {
      #pragma unroll
      for (int q2 = 0; q2 < 4; q2++) xn[q2] = ib[(size_t)(c0 + 4 + q2) * PLANE_A];
    }
    #pragma unroll
    for (int q2 = 0; q2 < 4; q2++) {
      int c = c0 + q2;
      float v = fmaxf(fmaf(xv[q2], sc[c], sh[c]), 0.f);
      const float* wc = wpt + (size_t)c * 180 + obase;  // uniform, contiguous x18
      #pragma unroll
      for (int o = 0; o < 18; o++)
        acc[o] = fmaf(wc[o], v, acc[o]);
    }
  }
  #pragma unroll
  for (int o = 0; o < 18; o++)
    out[((size_t)(b * 180 + obase + o)) * PLANE_A + pp] = acc[o];
  __shared__ float rs[4][18], rq[4][18];
  int wave = tid >> 6, lane = tid & 63;
  #pragma unroll
  for (int o = 0; o < 18; o++) {
    float s = acc[o], q = acc[o] * acc[o];
    #pragma unroll
    for (int off = 32; off > 0; off >>= 1) { s += __shfl_down(s, off); q += __shfl_down(q, off); }
    if (lane == 0) { rs[wave][o] = s; rq[wave][o] = q; }
  }
  __syncthreads();
  if (tid < 18)
    psum[(obase + tid) * 72 + posblk] = rs[0][tid] + rs[1][tid] + rs[2][tid] + rs[3][tid];
  else if (tid < 36) {
    int o = tid - 18;
    psq[(obase + o) * 72 + posblk] = rq[0][o] + rq[1][o] + rq[2][o] + rq[3][o];
  }
}

// ===== final: 1x1 conv 180->9 (transposed wt) + softmax + expectation =====
__global__ __launch_bounds__(256) void k_final(const float* __restrict__ in,
    const float* __restrict__ sc, const float* __restrict__ sh,
    const float* __restrict__ wpt, float* __restrict__ out) {
  int tid = threadIdx.x;
  int t = blockIdx.x * 256 + tid;
  int b = t / PLANE_A, p = t - b * PLANE_A;
  const float* ib = in + (size_t)b * 180 * PLANE_A + p;
  float acc[9];
  #pragma unroll
  for (int o = 0; o < 9; o++) acc[o] = 0.f;
  float xn[4];
  #pragma unroll
  for (int q2 = 0; q2 < 4; q2++) xn[q2] = ib[(size_t)q2 * PLANE_A];
  #pragma unroll 1
  for (int c0 = 0; c0 < 180; c0 += 4) {
    float xv[4];
    #pragma unroll
    for (int q2 = 0; q2 < 4; q2++) xv[q2] = xn[q2];
    if (c0 + 4 < 180) {
      #pragma unroll
      for (int q2 = 0; q2 < 4; q2++) xn[q2] = ib[(size_t)(c0 + 4 + q2) * PLANE_A];
    }
    #pragma unroll
    for (int q2 = 0; q2 < 4; q2++) {
      int c = c0 + q2;
      float v = fmaxf(fmaf(xv[q2], sc[c], sh[c]), 0.f);
      const float* wc = wpt + (size_t)c * 9;        // uniform, contiguous x9
      #pragma unroll
      for (int o = 0; o < 9; o++) acc[o] = fmaf(wc[o], v, acc[o]);
    }
  }
  float m = acc[0];
  #pragma unroll
  for (int o = 1; o < 9; o++) m = fmaxf(m, acc[o]);
  float se = 0.f, num = 0.f;
  #pragma unroll
  for (int o = 0; o < 9; o++) {
    float e = expf(acc[o] - m);
    se += e;
    num += (float)(o - 4) * e;
  }
  out[t] = num / se;
}

extern "C" void kernel_launch(void* const* d_in, const int* in_sizes, int n_in,
                              void* d_out, int out_size, void* d_ws, size_t ws_size,
                              hipStream_t stream) {
  const float* x    = (const float*)d_in[0];
  const float* fw0  = (const float*)d_in[1];
  const float* fg0  = (const float*)d_in[2];
  const float* fb0  = (const float*)d_in[3];
  const float* fw   = (const float*)d_in[4];
  const float* fg   = (const float*)d_in[5];
  const float* fb   = (const float*)d_in[6];
  const float* bcw  = (const float*)d_in[7];
  const float* a0dw = (const float*)d_in[8];
  const float* a0dg = (const float*)d_in[9];
  const float* a0db = (const float*)d_in[10];
  const float* a0pw = (const float*)d_in[11];
  const float* a0pg = (const float*)d_in[12];
  const float* a0pb = (const float*)d_in[13];
  const float* amdw = (const float*)d_in[14];
  const float* amdg = (const float*)d_in[15];
  const float* amdb = (const float*)d_in[16];
  const float* ampw = (const float*)d_in[17];
  const float* ampg = (const float*)d_in[18];
  const float* ampb = (const float*)d_in[19];
  const float* ldw  = (const float*)d_in[20];
  const float* ldg  = (const float*)d_in[21];
  const float* ldb  = (const float*)d_in[22];
  const float* lpw  = (const float*)d_in[23];
  float* outp = (float*)d_out;

  float* FA    = (float*)d_ws;
  float* FB    = FA + (size_t)BB * 7 * PLANE_F;
  float* CV    = FB + (size_t)BB * 7 * PLANE_F;
  float* GA    = CV + (size_t)BB * 144 * PLANE_A;
  float* GB    = GA + (size_t)BB * 180 * PLANE_A;
  float* PSUM  = GB + (size_t)BB * 180 * PLANE_A;   // 7*1458 / 180*72 both fit
  float* PSQ   = PSUM + 180 * 288;
  float* SC    = PSQ + 180 * 288;
  float* SH    = SC + 180;
  float* WT    = SH + 180;                           // 81648
  float* WPT   = WT + 81648;                         // 157140
  float* WPT_A0 = WPT;                               // [144][180]
  float* WPT_AM = WPT + 25920;                       // 4 x [180][180]
  float* WPT_L  = WPT + 25920 + 129600;              // [180][9]

  const float invNbig = 1.0f / (float)(BB * PLANE_F);
  const float invNsmall = 1.0f / (float)(BB * PLANE_A);

  // weight prep (BuildCost shuffle + pointwise transposes), one dispatch
  k_wprep<<<(238788 + 255) / 256, 256, 0, stream>>>(bcw, a0pw, ampw, lpw, WT, WPT);

  // feature extraction (SAI layout, fp32, vector row loads), stats fused
  k_featconv0<<<NBLK_FEAT, 256, 0, stream>>>(x, fw0, FA, PSUM, PSQ);
  k_bnfinal<<<7, 256, 0, stream>>>(PSUM, PSQ, fg0, fb0, SC, SH, NBLK_FEAT, invNbig);

  float* cur = FA; float* nxt = FB;
  for (int i = 0; i < 6; i++) {
    k_featconv4<<<NBLK_FEAT, 256, 0, stream>>>(cur, fw + i * 441, SC, SH, nxt, PSUM, PSQ);
    k_bnfinal<<<7, 256, 0, stream>>>(PSUM, PSQ, fg + i * 7, fb + i * 7, SC, SH, NBLK_FEAT, invNbig);
    float* tmp = cur; cur = nxt; nxt = tmp;
  }

  // BuildCost (16 outputs/block, SGPR weights, branchless dist-1 prefetch)
  k_buildcost<<<dim3(9, 36, 2), 256, 0, stream>>>(cur, SC, SH, WT, CV);

  // aggregation: dwconv 4-row strips (SGPR weights, vector loads), pwconv 18-out
  k_dwconv<false><<<BB * 144 * 9, 256, 0, stream>>>(CV, a0dw, nullptr, nullptr, GA, PSUM, PSQ, 144);
  k_bnfinal<<<144, 256, 0, stream>>>(PSUM, PSQ, a0dg, a0db, SC, SH, 18, invNsmall);
  k_pwconv<144><<<dim3(10, 72), 256, 0, stream>>>(GA, SC, SH, WPT_A0, GB, PSUM, PSQ);
  k_bnfinal<<<180, 256, 0, stream>>>(PSUM, PSQ, a0pg, a0pb, SC, SH, 72, invNsmall);

  for (int m = 0; m < 4; m++) {
    k_dwconv<true><<<BB * 180 * 9, 256, 0, stream>>>(GB, amdw + m * 1620, SC, SH, GA, PSUM, PSQ, 180);
    k_bnfinal<<<180, 256, 0, stream>>>(PSUM, PSQ, amdg + m * 180, amdb + m * 180, SC, SH, 18, invNsmall);
    k_pwconv<180><<<dim3(10, 72), 256, 0, stream>>>(GA, SC, SH, WPT_AM + m * 32400, GB, PSUM, PSQ);
    k_bnfinal<<<180, 256, 0, stream>>>(PSUM, PSQ, ampg + m * 180, ampb + m * 180, SC, SH, 72, invNsmall);
  }

  k_dwconv<true><<<BB * 180 * 9, 256, 0, stream>>>(GB, ldw, SC, SH, GA, PSUM, PSQ, 180);
  k_bnfinal<<<180, 256, 0, stream>>>(PSUM, PSQ, ldg, ldb, SC, SH, 18, invNsmall);

  k_final<<<72, 256, 0, stream>>>(GA, SC, SH, WPT_L, outp);
}

// Round 16
// 704.527 us; speedup vs baseline: 1.1517x; 1.0871x over previous
//
#include <hip/hip_runtime.h>

#define ANG 9
#define HH 96
#define BB 2
#define PLANE_F (81*HH*HH)  // 746496 per channel (81 views x 96x96)
#define PLANE_A (HH*HH)     // 9216
#define NBLK_FEAT 1458      // BB*81*9 blocks (each: 256 threads, 4-row strips)
#define INV_NSMALL (1.0f / 18432.0f)

typedef float f4 __attribute__((ext_vector_type(4), aligned(4)));

__device__ __forceinline__ void row3sel(const float* rp, int base, bool j0, bool j95,
                                        float& w0, float& w1, float& w2) {
  f4 v = *(const f4*)(rp + base);
  w0 = j95 ? v.z : v.x;
  w1 = j0 ? v.x : (j95 ? v.w : v.y);
  w2 = j0 ? v.y : v.z;
}

// ===== BN-final for feature stages (kept: prologue fusion here is the R7 disease) =====
__global__ __launch_bounds__(256) void k_bnfinal(const float* __restrict__ psum,
    const float* __restrict__ psq, const float* __restrict__ g, const float* __restrict__ bbias,
    float* __restrict__ sc, float* __restrict__ sh, int NB, float invN) {
  int c = blockIdx.x, tid = threadIdx.x;
  float s = 0.f, q = 0.f;
  for (int k = tid; k < NB; k += 256) { s += psum[c * NB + k]; q += psq[c * NB + k]; }
  __shared__ float ss[256], qq[256];
  ss[tid] = s; qq[tid] = q;
  __syncthreads();
  for (int st = 128; st > 0; st >>= 1) {
    if (tid < st) { ss[tid] += ss[tid + st]; qq[tid] += qq[tid + st]; }
    __syncthreads();
  }
  if (tid == 0) {
    float mean = ss[0] * invN;
    float var = fmaxf(qq[0] * invN - mean * mean, 0.f);
    float scale = g[c] / sqrtf(var + 1e-5f);
    sc[c] = scale; sh[c] = bbias[c] - mean * scale;
  }
}

// ===== weight prep: BuildCost shuffle + pointwise transposes, one dispatch =====
__global__ __launch_bounds__(256) void k_wprep(const float* __restrict__ bcw,
    const float* __restrict__ a0pw, const float* __restrict__ ampw, const float* __restrict__ lpw,
    float* __restrict__ wt, float* __restrict__ wpt) {
  int k = blockIdx.x * 256 + threadIdx.x;
  if (k < 81648) {
    int o = k & 15; int rest = k >> 4;
    int r81 = rest % 81; int gc = rest / 81;
    int c = gc % 7, g = gc / 7;
    wt[k] = bcw[((g * 16 + o) * 7 + c) * 81 + r81];
    return;
  }
  int t = k - 81648;
  if (t < 25920) {
    int c = t / 180, o = t % 180;
    wpt[t] = a0pw[o * 144 + c];
  } else if (t < 25920 + 129600) {
    int t2 = t - 25920;
    int m = t2 / 32400, r = t2 % 32400;
    int c = r / 180, o = r % 180;
    wpt[t] = ampw[m * 32400 + o * 180 + c];
  } else if (t < 25920 + 129600 + 1620) {
    int t2 = t - 25920 - 129600;
    int c = t2 / 9, o = t2 % 9;
    wpt[t] = lpw[o * 180 + c];
  }
}

// ===== feature conv0: 1->7 from raw x, vector row loads, fused stats =====
__global__ __launch_bounds__(256) void k_featconv0(const float* __restrict__ x,
    const float* __restrict__ w, float* __restrict__ out,
    float* __restrict__ psum, float* __restrict__ psq) {
  int blk = blockIdx.x, tid = threadIdx.x;
  int view = blk / 9, q = blk % 9;
  int b = view / 81, uv = view % 81;
  int u = uv / 9, v = uv % 9;
  int widx = q * 256 + tid;
  int j = widx % HH, i0 = (widx / HH) * 4;
  bool j0 = (j == 0), j95 = (j == 95);
  int base = j0 ? 0 : (j95 ? 92 : j - 1);
  float me0 = j0 ? 0.f : 1.f, me2 = j95 ? 0.f : 1.f;
  const float* bx = x + (size_t)b * PLANE_F + (u * HH) * 864 + v * HH;
  float win[6][3];
  #pragma unroll
  for (int r6 = 0; r6 < 6; r6++) {
    int ii = i0 + r6 - 1;
    float mi = ((unsigned)ii < 96u) ? 1.f : 0.f;
    int iic = min(max(ii, 0), 95);
    float w0, w1, w2;
    row3sel(bx + iic * 864, base, j0, j95, w0, w1, w2);
    win[r6][0] = w0 * (mi * me0);
    win[r6][1] = w1 * mi;
    win[r6][2] = w2 * (mi * me2);
  }
  float acc[4][7];
  #pragma unroll
  for (int px = 0; px < 4; px++)
    #pragma unroll
    for (int o = 0; o < 7; o++) acc[px][o] = 0.f;
  #pragma unroll
  for (int o = 0; o < 7; o++) {
    const float* wc = w + o * 9;
    #pragma unroll
    for (int ky = 0; ky < 3; ky++)
      #pragma unroll
      for (int kx = 0; kx < 3; kx++) {
        float wv = wc[ky * 3 + kx];
        #pragma unroll
        for (int px = 0; px < 4; px++)
          acc[px][o] = fmaf(win[px + ky][kx], wv, acc[px][o]);
      }
  }
  #pragma unroll
  for (int o = 0; o < 7; o++) {
    float* op = out + ((size_t)(b * 7 + o)) * PLANE_F + uv * PLANE_A + i0 * HH + j;
    #pragma unroll
    for (int px = 0; px < 4; px++) op[px * HH] = acc[px][o];
  }
  float sv[7], qv[7];
  #pragma unroll
  for (int o = 0; o < 7; o++) {
    sv[o] = acc[0][o] + acc[1][o] + acc[2][o] + acc[3][o];
    qv[o] = acc[0][o]*acc[0][o] + acc[1][o]*acc[1][o] + acc[2][o]*acc[2][o] + acc[3][o]*acc[3][o];
  }
  #pragma unroll
  for (int off2 = 32; off2 > 0; off2 >>= 1)
    #pragma unroll
    for (int o = 0; o < 7; o++) { sv[o] += __shfl_down(sv[o], off2); qv[o] += __shfl_down(qv[o], off2); }
  __shared__ float red[4][14];
  int wave = tid >> 6, lane = tid & 63;
  if (lane == 0) {
    #pragma unroll
    for (int o = 0; o < 7; o++) { red[wave][o] = sv[o]; red[wave][7 + o] = qv[o]; }
  }
  __syncthreads();
  if (tid < 14) {
    float t4 = red[0][tid] + red[1][tid] + red[2][tid] + red[3][tid];
    if (tid < 7) psum[tid * NBLK_FEAT + blk] = t4;
    else         psq[(tid - 7) * NBLK_FEAT + blk] = t4;
  }
}

// ===== feature conv: 7->7, vector row loads + channel prefetch, fused stats =====
__global__ __launch_bounds__(256) void k_featconv4(const float* __restrict__ in,
    const float* __restrict__ w, const float* __restrict__ sc, const float* __restrict__ sh,
    float* __restrict__ out, float* __restrict__ psum, float* __restrict__ psq) {
  int blk = blockIdx.x, tid = threadIdx.x;
  int view = blk / 9, q = blk % 9;
  int b = view / 81, uv = view % 81;
  int widx = q * 256 + tid;
  int j = widx % HH, i0 = (widx / HH) * 4;
  bool j0 = (j == 0), j95 = (j == 95);
  int base = j0 ? 0 : (j95 ? 92 : j - 1);
  float me0 = j0 ? 0.f : 1.f, me2 = j95 ? 0.f : 1.f;
  float mrow[6]; int roff[6];
  #pragma unroll
  for (int r6 = 0; r6 < 6; r6++) {
    int ii = i0 + r6 - 1;
    mrow[r6] = ((unsigned)ii < 96u) ? 1.f : 0.f;
    roff[r6] = min(max(ii, 0), 95) * HH + base;
  }
  float acc[4][7];
  #pragma unroll
  for (int px = 0; px < 4; px++)
    #pragma unroll
    for (int o = 0; o < 7; o++) acc[px][o] = 0.f;
  const float* ipbase = in + ((size_t)(b * 7)) * PLANE_F + uv * PLANE_A;
  float pre[6][3];
  #pragma unroll
  for (int r6 = 0; r6 < 6; r6++)
    row3sel(ipbase + roff[r6], 0, j0, j95, pre[r6][0], pre[r6][1], pre[r6][2]);
  #pragma unroll 1
  for (int c = 0; c < 7; c++) {
    float s = sc[c], h2 = sh[c];
    float win[6][3];
    #pragma unroll
    for (int r6 = 0; r6 < 6; r6++) {
      win[r6][0] = fmaxf(fmaf(pre[r6][0], s, h2), 0.f) * (mrow[r6] * me0);
      win[r6][1] = fmaxf(fmaf(pre[r6][1], s, h2), 0.f) * mrow[r6];
      win[r6][2] = fmaxf(fmaf(pre[r6][2], s, h2), 0.f) * (mrow[r6] * me2);
    }
    if (c < 6) {
      const float* ipn = ipbase + (size_t)(c + 1) * PLANE_F;
      #pragma unroll
      for (int r6 = 0; r6 < 6; r6++)
        row3sel(ipn + roff[r6], 0, j0, j95, pre[r6][0], pre[r6][1], pre[r6][2]);
    }
    #pragma unroll
    for (int o = 0; o < 7; o++) {
      const float* wc = w + (o * 7 + c) * 9;
      #pragma unroll
      for (int ky = 0; ky < 3; ky++)
        #pragma unroll
        for (int kx = 0; kx < 3; kx++) {
          float wv = wc[ky * 3 + kx];
          #pragma unroll
          for (int px = 0; px < 4; px++)
            acc[px][o] = fmaf(win[px + ky][kx], wv, acc[px][o]);
        }
    }
  }
  #pragma unroll
  for (int o = 0; o < 7; o++) {
    float* op = out + ((size_t)(b * 7 + o)) * PLANE_F + uv * PLANE_A + i0 * HH + j;
    #pragma unroll
    for (int px = 0; px < 4; px++) op[px * HH] = acc[px][o];
  }
  float sv[7], qv[7];
  #pragma unroll
  for (int o = 0; o < 7; o++) {
    sv[o] = acc[0][o] + acc[1][o] + acc[2][o] + acc[3][o];
    qv[o] = acc[0][o]*acc[0][o] + acc[1][o]*acc[1][o] + acc[2][o]*acc[2][o] + acc[3][o]*acc[3][o];
  }
  #pragma unroll
  for (int off2 = 32; off2 > 0; off2 >>= 1)
    #pragma unroll
    for (int o = 0; o < 7; o++) { sv[o] += __shfl_down(sv[o], off2); qv[o] += __shfl_down(qv[o], off2); }
  __shared__ float red[4][14];
  int wave = tid >> 6, lane = tid & 63;
  if (lane == 0) {
    #pragma unroll
    for (int o = 0; o < 7; o++) { red[wave][o] = sv[o]; red[wave][7 + o] = qv[o]; }
  }
  __syncthreads();
  if (tid < 14) {
    float t4 = red[0][tid] + red[1][tid] + red[2][tid] + red[3][tid];
    if (tid < 7) psum[tid * NBLK_FEAT + blk] = t4;
    else         psq[(tid - 7) * NBLK_FEAT + blk] = t4;
  }
}

// ===== BuildCost helper: branchless clamped 9-tap load (R6-proven) =====
__device__ __forceinline__ void bc_load(const float* __restrict__ F, int b, int c, int u,
    int d, int i, int j, float* raw, float* msk) {
  const float* Fc = F + ((size_t)(b * 7 + c)) * PLANE_F + (u * 9) * PLANE_A;
  int ii = i + d * (4 - u);
  float mi = ((unsigned)ii < 96u) ? 1.f : 0.f;
  int iic = min(max(ii, 0), 95);
  const float* Frow = Fc + iic * HH;
  #pragma unroll
  for (int v = 0; v < 9; v++) {
    int jj = j + d * (4 - v);
    float mj = ((unsigned)jj < 96u) ? 1.f : 0.f;
    int jjc = min(max(jj, 0), 95);
    raw[v] = Frow[v * PLANE_A + jjc];
    msk[v] = mi * mj;
  }
}

// ===== BuildCost: 16-o, c-split halves (c0-3 / c4-6) for occupancy =====
// grid (9, 36, 4): x = g, y = pos block, z = b*2+half. Partial sums into cva/cvb.
__global__ __launch_bounds__(256) void k_buildcost(const float* __restrict__ F,
    const float* __restrict__ sc, const float* __restrict__ sh,
    const float* __restrict__ wt, float* __restrict__ cva, float* __restrict__ cvb) {
  int g = blockIdx.x, tid = threadIdx.x;
  int b = blockIdx.z >> 1, half = blockIdx.z & 1;
  int c0 = half ? 4 : 0;
  int ncu = half ? 27 : 36;                          // (7-4)*9 / 4*9
  int d = g - 4;
  bool flip = d > 0;
  int p = blockIdx.y * 256 + tid;
  int i = p / HH, j = p % HH;
  float acc[16];
  #pragma unroll
  for (int o = 0; o < 16; o++) acc[o] = 0.f;
  float raw[9], msk[9];
  bc_load(F, b, c0, 0, d, i, j, raw, msk);
  #pragma unroll 1
  for (int cu = 0; cu < ncu; cu++) {
    int c = c0 + cu / 9, u = cu % 9;
    float cr[9], cm[9];
    #pragma unroll
    for (int v = 0; v < 9; v++) { cr[v] = raw[v]; cm[v] = msk[v]; }
    if (cu + 1 < ncu) {
      int cn = c0 + (cu + 1) / 9, un = (cu + 1) % 9;
      bc_load(F, b, cn, un, d, i, j, raw, msk);
    }
    float s = sc[c], h2 = sh[c];
    int uw = flip ? 8 - u : u;
    const float* wbase = wt + ((size_t)((g * 7 + c) * 81 + uw * 9)) * 16;
    #pragma unroll
    for (int v = 0; v < 9; v++) {
      float a = fmaxf(fmaf(cr[v], s, h2), 0.f) * cm[v];
      int vw = flip ? 8 - v : v;
      const float* wp = wbase + vw * 16;            // uniform -> s_load
      #pragma unroll
      for (int o = 0; o < 16; o++) acc[o] = fmaf(wp[o], a, acc[o]);
    }
  }
  float* cv = half ? cvb : cva;
  size_t cvbase = ((size_t)(b * 144 + g * 16)) * PLANE_A + p;
  #pragma unroll
  for (int o = 0; o < 16; o++) cv[cvbase + o * PLANE_A] = acc[o];
}

// ===== depthwise 3x3: 4-row strips, SGPR weights, fused BN prologue + stats =====
// AFF: prologue reduces pps/ppq[c*72 + k] (72 vals, block-uniform c) -> scale/shift.
// SUM2: conv input = in + in2 (BuildCost partial halves).
// grid: BB*C*9 blocks; blk = (b*C + c)*9 + q. Stats out: dps[c*18 + b*9 + q].
template<bool AFF, bool SUM2>
__global__ __launch_bounds__(256) void k_dwconv(const float* __restrict__ in,
    const float* __restrict__ in2, const float* __restrict__ w,
    const float* __restrict__ pps, const float* __restrict__ ppq,
    const float* __restrict__ g, const float* __restrict__ bbias,
    float* __restrict__ out, float* __restrict__ dps, float* __restrict__ dpq, int C) {
  int blk = blockIdx.x, tid = threadIdx.x;
  int q = blk % 9; int rr = blk / 9; int c = rr % C; int b = rr / C;
  __shared__ float scsh[2];
  float s = 1.f, h2 = 0.f;
  if (AFF) {
    float si = 0.f, qi = 0.f;
    if (tid < 64) {
      si = pps[c * 72 + tid]; qi = ppq[c * 72 + tid];
      if (tid < 8) { si += pps[c * 72 + 64 + tid]; qi += ppq[c * 72 + 64 + tid]; }
    }
    #pragma unroll
    for (int off = 32; off > 0; off >>= 1) { si += __shfl_down(si, off); qi += __shfl_down(qi, off); }
    if (tid == 0) {
      float mean = si * INV_NSMALL;
      float var = fmaxf(qi * INV_NSMALL - mean * mean, 0.f);
      float scale = g[c] / sqrtf(var + 1e-5f);
      scsh[0] = scale; scsh[1] = bbias[c] - mean * scale;
    }
    __syncthreads();
    s = scsh[0]; h2 = scsh[1];
  }
  int widx = q * 256 + tid;
  int j = widx % HH, i0 = (widx / HH) * 4;
  bool j0 = (j == 0), j95 = (j == 95);
  int base = j0 ? 0 : (j95 ? 92 : j - 1);
  float me0 = j0 ? 0.f : 1.f, me2 = j95 ? 0.f : 1.f;
  const float* wc = w + c * 9;                      // uniform -> s_load
  const float* ip = in + ((size_t)(b * C + c)) * PLANE_A;
  const float* ip2 = SUM2 ? in2 + ((size_t)(b * C + c)) * PLANE_A : nullptr;
  float win[6][3];
  #pragma unroll
  for (int r6 = 0; r6 < 6; r6++) {
    int ii = i0 + r6 - 1;
    float mi = ((unsigned)ii < 96u) ? 1.f : 0.f;
    int iic = min(max(ii, 0), 95);
    float w0, w1, w2;
    row3sel(ip + iic * HH, base, j0, j95, w0, w1, w2);
    if (SUM2) {
      float x0, x1, x2;
      row3sel(ip2 + iic * HH, base, j0, j95, x0, x1, x2);
      w0 += x0; w1 += x1; w2 += x2;
    }
    if (AFF) {
      w0 = fmaxf(fmaf(w0, s, h2), 0.f);
      w1 = fmaxf(fmaf(w1, s, h2), 0.f);
      w2 = fmaxf(fmaf(w2, s, h2), 0.f);
    }
    win[r6][0] = w0 * (mi * me0);
    win[r6][1] = w1 * mi;
    win[r6][2] = w2 * (mi * me2);
  }
  float acc[4];
  #pragma unroll
  for (int px = 0; px < 4; px++) acc[px] = 0.f;
  #pragma unroll
  for (int ky = 0; ky < 3; ky++)
    #pragma unroll
    for (int kx = 0; kx < 3; kx++) {
      float wv = wc[ky * 3 + kx];
      #pragma unroll
      for (int px = 0; px < 4; px++)
        acc[px] = fmaf(win[px + ky][kx], wv, acc[px]);
    }
  float* op = out + ((size_t)(b * C + c)) * PLANE_A + i0 * HH + j;
  #pragma unroll
  for (int px = 0; px < 4; px++) op[px * HH] = acc[px];
  float sv = acc[0] + acc[1] + acc[2] + acc[3];
  float qv = acc[0]*acc[0] + acc[1]*acc[1] + acc[2]*acc[2] + acc[3]*acc[3];
  #pragma unroll
  for (int off2 = 32; off2 > 0; off2 >>= 1) { sv += __shfl_down(sv, off2); qv += __shfl_down(qv, off2); }
  __shared__ float red[4][2];
  int wave = tid >> 6, lane = tid & 63;
  if (lane == 0) { red[wave][0] = sv; red[wave][1] = qv; }
  __syncthreads();
  if (tid == 0) {
    float S = red[0][0] + red[1][0] + red[2][0] + red[3][0];
    float Q = red[0][1] + red[1][1] + red[2][1] + red[3][1];
    dps[c * 18 + b * 9 + q] = S;
    dpq[c * 18 + b * 9 + q] = Q;
  }
}

// ===== pointwise conv: fused BN prologue (dps[c*18+k]) + 18 out/thread =====
// grid (10, 72): x = output group (18 outputs), y = position block
template<int K>
__global__ __launch_bounds__(256) void k_pwconv(const float* __restrict__ in,
    const float* __restrict__ dps, const float* __restrict__ dpq,
    const float* __restrict__ g, const float* __restrict__ bbias,
    const float* __restrict__ wpt, float* __restrict__ out,
    float* __restrict__ pps, float* __restrict__ ppq) {
  int tid = threadIdx.x;
  __shared__ float2 scsh[K];
  if (tid < K) {
    float S = 0.f, Q = 0.f;
    #pragma unroll 1
    for (int k = 0; k < 18; k++) { S += dps[tid * 18 + k]; Q += dpq[tid * 18 + k]; }
    float mean = S * INV_NSMALL;
    float var = fmaxf(Q * INV_NSMALL - mean * mean, 0.f);
    float scale = g[tid] / sqrtf(var + 1e-5f);
    scsh[tid] = make_float2(scale, bbias[tid] - mean * scale);
  }
  __syncthreads();
  int posblk = blockIdx.y;
  int p = posblk * 256 + tid;
  int b = p / PLANE_A, pp = p - b * PLANE_A;
  int obase = blockIdx.x * 18;
  float acc[18];
  #pragma unroll
  for (int o = 0; o < 18; o++) acc[o] = 0.f;
  const float* ib = in + (size_t)b * K * PLANE_A + pp;
  float xn[4];
  #pragma unroll
  for (int q2 = 0; q2 < 4; q2++) xn[q2] = ib[(size_t)q2 * PLANE_A];
  #pragma unroll 1
  for (int c0 = 0; c0 < K; c0 += 4) {
    float xv[4];
    #pragma unroll
    for (int q2 = 0; q2 < 4; q2++) xv[q2] = xn[q2];
    if (c0 + 4 < K) {
      #pragma unroll
      for (int q2 = 0; q2 < 4; q2++) xn[q2] = ib[(size_t)(c0 + 4 + q2) * PLANE_A];
    }
    #pragma unroll
    for (int q2 = 0; q2 < 4; q2++) {
      int c = c0 + q2;
      float2 ss = scsh[c];
      float v = fmaxf(fmaf(xv[q2], ss.x, ss.y), 0.f);
      const float* wc = wpt + (size_t)c * 180 + obase;  // uniform, contiguous x18
      #pragma unroll
      for (int o = 0; o < 18; o++)
        acc[o] = fmaf(wc[o], v, acc[o]);
    }
  }
  #pragma unroll
  for (int o = 0; o < 18; o++)
    out[((size_t)(b * 180 + obase + o)) * PLANE_A + pp] = acc[o];
  __shared__ float rs[4][18], rq[4][18];
  int wave = tid >> 6, lane = tid & 63;
  #pragma unroll
  for (int o = 0; o < 18; o++) {
    float s = acc[o], q = acc[o] * acc[o];
    #pragma unroll
    for (int off = 32; off > 0; off >>= 1) { s += __shfl_down(s, off); q += __shfl_down(q, off); }
    if (lane == 0) { rs[wave][o] = s; rq[wave][o] = q; }
  }
  __syncthreads();
  if (tid < 18)
    pps[(obase + tid) * 72 + posblk] = rs[0][tid] + rs[1][tid] + rs[2][tid] + rs[3][tid];
  else if (tid < 36) {
    int o = tid - 18;
    ppq[(obase + o) * 72 + posblk] = rq[0][o] + rq[1][o] + rq[2][o] + rq[3][o];
  }
}

// ===== final: fused BN prologue (dps[c*18+k]) + 1x1 180->9 + softmax + E[d] =====
__global__ __launch_bounds__(256) void k_final(const float* __restrict__ in,
    const float* __restrict__ dps, const float* __restrict__ dpq,
    const float* __restrict__ g, const float* __restrict__ bbias,
    const float* __restrict__ wpt, float* __restrict__ out) {
  int tid = threadIdx.x;
  __shared__ float2 scsh[180];
  if (tid < 180) {
    float S = 0.f, Q = 0.f;
    #pragma unroll 1
    for (int k = 0; k < 18; k++) { S += dps[tid * 18 + k]; Q += dpq[tid * 18 + k]; }
    float mean = S * INV_NSMALL;
    float var = fmaxf(Q * INV_NSMALL - mean * mean, 0.f);
    float scale = g[tid] / sqrtf(var + 1e-5f);
    scsh[tid] = make_float2(scale, bbias[tid] - mean * scale);
  }
  __syncthreads();
  int t = blockIdx.x * 256 + tid;
  int b = t / PLANE_A, p = t - b * PLANE_A;
  const float* ib = in + (size_t)b * 180 * PLANE_A + p;
  float acc[9];
  #pragma unroll
  for (int o = 0; o < 9; o++) acc[o] = 0.f;
  float xn[4];
  #pragma unroll
  for (int q2 = 0; q2 < 4; q2++) xn[q2] = ib[(size_t)q2 * PLANE_A];
  #pragma unroll 1
  for (int c0 = 0; c0 < 180; c0 += 4) {
    float xv[4];
    #pragma unroll
    for (int q2 = 0; q2 < 4; q2++) xv[q2] = xn[q2];
    if (c0 + 4 < 180) {
      #pragma unroll
      for (int q2 = 0; q2 < 4; q2++) xn[q2] = ib[(size_t)(c0 + 4 + q2) * PLANE_A];
    }
    #pragma unroll
    for (int q2 = 0; q2 < 4; q2++) {
      int c = c0 + q2;
      float2 ss = scsh[c];
      float v = fmaxf(fmaf(xv[q2], ss.x, ss.y), 0.f);
      const float* wc = wpt + (size_t)c * 9;        // uniform, contiguous x9
      #pragma unroll
      for (int o = 0; o < 9; o++) acc[o] = fmaf(wc[o], v, acc[o]);
    }
  }
  float m = acc[0];
  #pragma unroll
  for (int o = 1; o < 9; o++) m = fmaxf(m, acc[o]);
  float se = 0.f, num = 0.f;
  #pragma unroll
  for (int o = 0; o < 9; o++) {
    float e = expf(acc[o] - m);
    se += e;
    num += (float)(o - 4) * e;
  }
  out[t] = num / se;
}

extern "C" void kernel_launch(void* const* d_in, const int* in_sizes, int n_in,
                              void* d_out, int out_size, void* d_ws, size_t ws_size,
                              hipStream_t stream) {
  const float* x    = (const float*)d_in[0];
  const float* fw0  = (const float*)d_in[1];
  const float* fg0  = (const float*)d_in[2];
  const float* fb0  = (const float*)d_in[3];
  const float* fw   = (const float*)d_in[4];
  const float* fg   = (const float*)d_in[5];
  const float* fb   = (const float*)d_in[6];
  const float* bcw  = (const float*)d_in[7];
  const float* a0dw = (const float*)d_in[8];
  const float* a0dg = (const float*)d_in[9];
  const float* a0db = (const float*)d_in[10];
  const float* a0pw = (const float*)d_in[11];
  const float* a0pg = (const float*)d_in[12];
  const float* a0pb = (const float*)d_in[13];
  const float* amdw = (const float*)d_in[14];
  const float* amdg = (const float*)d_in[15];
  const float* amdb = (const float*)d_in[16];
  const float* ampw = (const float*)d_in[17];
  const float* ampg = (const float*)d_in[18];
  const float* ampb = (const float*)d_in[19];
  const float* ldw  = (const float*)d_in[20];
  const float* ldg  = (const float*)d_in[21];
  const float* ldb  = (const float*)d_in[22];
  const float* lpw  = (const float*)d_in[23];
  float* outp = (float*)d_out;

  float* FA    = (float*)d_ws;
  float* FB    = FA + (size_t)BB * 7 * PLANE_F;
  float* CVA   = FB + (size_t)BB * 7 * PLANE_F;
  float* CVB   = CVA + (size_t)BB * 144 * PLANE_A;
  float* GA    = CVB + (size_t)BB * 144 * PLANE_A;
  float* GB    = GA + (size_t)BB * 180 * PLANE_A;
  float* PSUM  = GB + (size_t)BB * 180 * PLANE_A;   // feat: 7*1458; agg dps: 180*18
  float* PSQ   = PSUM + 180 * 288;
  float* PPS   = PSQ + 180 * 288;                    // pw stats: 180*72
  float* PPQ   = PPS + 180 * 72;
  float* SC    = PPQ + 180 * 72;
  float* SH    = SC + 180;
  float* WT    = SH + 180;                           // 81648
  float* WPT   = WT + 81648;                         // 157140
  float* WPT_A0 = WPT;
  float* WPT_AM = WPT + 25920;
  float* WPT_L  = WPT + 25920 + 129600;

  const float invNbig = 1.0f / (float)(BB * PLANE_F);

  // weight prep (BuildCost shuffle + pointwise transposes), one dispatch
  k_wprep<<<(238788 + 255) / 256, 256, 0, stream>>>(bcw, a0pw, ampw, lpw, WT, WPT);

  // feature extraction (stats fused; bnfinal kept — prologue fusion too costly here)
  k_featconv0<<<NBLK_FEAT, 256, 0, stream>>>(x, fw0, FA, PSUM, PSQ);
  k_bnfinal<<<7, 256, 0, stream>>>(PSUM, PSQ, fg0, fb0, SC, SH, NBLK_FEAT, invNbig);

  float* cur = FA; float* nxt = FB;
  for (int i = 0; i < 6; i++) {
    k_featconv4<<<NBLK_FEAT, 256, 0, stream>>>(cur, fw + i * 441, SC, SH, nxt, PSUM, PSQ);
    k_bnfinal<<<7, 256, 0, stream>>>(PSUM, PSQ, fg + i * 7, fb + i * 7, SC, SH, NBLK_FEAT, invNbig);
    float* tmp = cur; cur = nxt; nxt = tmp;
  }

  // BuildCost: c-split halves for occupancy (partials summed in dwconv)
  k_buildcost<<<dim3(9, 36, 4), 256, 0, stream>>>(cur, SC, SH, WT, CVA, CVB);

  // aggregation: BN prologues fused into consumers (no agg bnfinal dispatches)
  k_dwconv<false, true><<<BB * 144 * 9, 256, 0, stream>>>(CVA, CVB, a0dw,
      nullptr, nullptr, nullptr, nullptr, GA, PSUM, PSQ, 144);
  k_pwconv<144><<<dim3(10, 72), 256, 0, stream>>>(GA, PSUM, PSQ, a0dg, a0db,
      WPT_A0, GB, PPS, PPQ);

  for (int m = 0; m < 4; m++) {
    const float* pg = (m == 0) ? a0pg : ampg + (m - 1) * 180;
    const float* pb = (m == 0) ? a0pb : ampb + (m - 1) * 180;
    k_dwconv<true, false><<<BB * 180 * 9, 256, 0, stream>>>(GB, nullptr, amdw + m * 1620,
        PPS, PPQ, pg, pb, GA, PSUM, PSQ, 180);
    k_pwconv<180><<<dim3(10, 72), 256, 0, stream>>>(GA, PSUM, PSQ,
        amdg + m * 180, amdb + m * 180, WPT_AM + m * 32400, GB, PPS, PPQ);
  }

  k_dwconv<true, false><<<BB * 180 * 9, 256, 0, stream>>>(GB, nullptr, ldw,
      PPS, PPQ, ampg + 540, ampb + 540, GA, PSUM, PSQ, 180);

  k_final<<<72, 256, 0, stream>>>(GA, PSUM, PSQ, ldg, ldb, WPT_L, outp);
}

// Round 17
// 680.262 us; speedup vs baseline: 1.1928x; 1.0357x over previous
//
#include <hip/hip_runtime.h>

#define ANG 9
#define HH 96
#define BB 2
#define PLANE_F (81*HH*HH)  // 746496 per channel (81 views x 96x96)
#define PLANE_A (HH*HH)     // 9216
#define NBLK_FEAT 1458      // BB*81*9 blocks (each: 256 threads, 4-row strips)
#define INV_NSMALL (1.0f / 18432.0f)

typedef float f4 __attribute__((ext_vector_type(4), aligned(4)));

__device__ __forceinline__ void row3sel(const float* rp, int base, bool j0, bool j95,
                                        float& w0, float& w1, float& w2) {
  f4 v = *(const f4*)(rp + base);
  w0 = j95 ? v.z : v.x;
  w1 = j0 ? v.x : (j95 ? v.w : v.y);
  w2 = j0 ? v.y : v.z;
}

// ===== BN-final for feature stages =====
__global__ __launch_bounds__(256) void k_bnfinal(const float* __restrict__ psum,
    const float* __restrict__ psq, const float* __restrict__ g, const float* __restrict__ bbias,
    float* __restrict__ sc, float* __restrict__ sh, int NB, float invN) {
  int c = blockIdx.x, tid = threadIdx.x;
  float s = 0.f, q = 0.f;
  for (int k = tid; k < NB; k += 256) { s += psum[c * NB + k]; q += psq[c * NB + k]; }
  __shared__ float ss[256], qq[256];
  ss[tid] = s; qq[tid] = q;
  __syncthreads();
  for (int st = 128; st > 0; st >>= 1) {
    if (tid < st) { ss[tid] += ss[tid + st]; qq[tid] += qq[tid + st]; }
    __syncthreads();
  }
  if (tid == 0) {
    float mean = ss[0] * invN;
    float var = fmaxf(qq[0] * invN - mean * mean, 0.f);
    float scale = g[c] / sqrtf(var + 1e-5f);
    sc[c] = scale; sh[c] = bbias[c] - mean * scale;
  }
}

// ===== weight prep: BuildCost shuffle + pointwise transposes, one dispatch =====
__global__ __launch_bounds__(256) void k_wprep(const float* __restrict__ bcw,
    const float* __restrict__ a0pw, const float* __restrict__ ampw, const float* __restrict__ lpw,
    float* __restrict__ wt, float* __restrict__ wpt) {
  int k = blockIdx.x * 256 + threadIdx.x;
  if (k < 81648) {
    int o = k & 15; int rest = k >> 4;
    int r81 = rest % 81; int gc = rest / 81;
    int c = gc % 7, g = gc / 7;
    wt[k] = bcw[((g * 16 + o) * 7 + c) * 81 + r81];
    return;
  }
  int t = k - 81648;
  if (t < 25920) {
    int c = t / 180, o = t % 180;
    wpt[t] = a0pw[o * 144 + c];
  } else if (t < 25920 + 129600) {
    int t2 = t - 25920;
    int m = t2 / 32400, r = t2 % 32400;
    int c = r / 180, o = r % 180;
    wpt[t] = ampw[m * 32400 + o * 180 + c];
  } else if (t < 25920 + 129600 + 1620) {
    int t2 = t - 25920 - 129600;
    int c = t2 / 9, o = t2 % 9;
    wpt[t] = lpw[o * 180 + c];
  }
}

// ===== feature conv0: 1->7 from raw x, vector row loads, fused stats =====
__global__ __launch_bounds__(256, 4) void k_featconv0(const float* __restrict__ x,
    const float* __restrict__ w, float* __restrict__ out,
    float* __restrict__ psum, float* __restrict__ psq) {
  int blk = blockIdx.x, tid = threadIdx.x;
  int view = blk / 9, q = blk % 9;
  int b = view / 81, uv = view % 81;
  int u = uv / 9, v = uv % 9;
  int widx = q * 256 + tid;
  int j = widx % HH, i0 = (widx / HH) * 4;
  bool j0 = (j == 0), j95 = (j == 95);
  int base = j0 ? 0 : (j95 ? 92 : j - 1);
  float me0 = j0 ? 0.f : 1.f, me2 = j95 ? 0.f : 1.f;
  const float* bx = x + (size_t)b * PLANE_F + (u * HH) * 864 + v * HH;
  float win[6][3];
  #pragma unroll
  for (int r6 = 0; r6 < 6; r6++) {
    int ii = i0 + r6 - 1;
    float mi = ((unsigned)ii < 96u) ? 1.f : 0.f;
    int iic = min(max(ii, 0), 95);
    float w0, w1, w2;
    row3sel(bx + iic * 864, base, j0, j95, w0, w1, w2);
    win[r6][0] = w0 * (mi * me0);
    win[r6][1] = w1 * mi;
    win[r6][2] = w2 * (mi * me2);
  }
  float acc[4][7];
  #pragma unroll
  for (int px = 0; px < 4; px++)
    #pragma unroll
    for (int o = 0; o < 7; o++) acc[px][o] = 0.f;
  #pragma unroll
  for (int o = 0; o < 7; o++) {
    const float* wc = w + o * 9;
    #pragma unroll
    for (int ky = 0; ky < 3; ky++)
      #pragma unroll
      for (int kx = 0; kx < 3; kx++) {
        float wv = wc[ky * 3 + kx];
        #pragma unroll
        for (int px = 0; px < 4; px++)
          acc[px][o] = fmaf(win[px + ky][kx], wv, acc[px][o]);
      }
  }
  #pragma unroll
  for (int o = 0; o < 7; o++) {
    float* op = out + ((size_t)(b * 7 + o)) * PLANE_F + uv * PLANE_A + i0 * HH + j;
    #pragma unroll
    for (int px = 0; px < 4; px++) op[px * HH] = acc[px][o];
  }
  float sv[7], qv[7];
  #pragma unroll
  for (int o = 0; o < 7; o++) {
    sv[o] = acc[0][o] + acc[1][o] + acc[2][o] + acc[3][o];
    qv[o] = acc[0][o]*acc[0][o] + acc[1][o]*acc[1][o] + acc[2][o]*acc[2][o] + acc[3][o]*acc[3][o];
  }
  #pragma unroll
  for (int off2 = 32; off2 > 0; off2 >>= 1)
    #pragma unroll
    for (int o = 0; o < 7; o++) { sv[o] += __shfl_down(sv[o], off2); qv[o] += __shfl_down(qv[o], off2); }
  __shared__ float red[4][14];
  int wave = tid >> 6, lane = tid & 63;
  if (lane == 0) {
    #pragma unroll
    for (int o = 0; o < 7; o++) { red[wave][o] = sv[o]; red[wave][7 + o] = qv[o]; }
  }
  __syncthreads();
  if (tid < 14) {
    float t4 = red[0][tid] + red[1][tid] + red[2][tid] + red[3][tid];
    if (tid < 7) psum[tid * NBLK_FEAT + blk] = t4;
    else         psq[(tid - 7) * NBLK_FEAT + blk] = t4;
  }
}

// ===== feature conv: 7->7, vector row loads + channel prefetch, fused stats =====
__global__ __launch_bounds__(256, 4) void k_featconv4(const float* __restrict__ in,
    const float* __restrict__ w, const float* __restrict__ sc, const float* __restrict__ sh,
    float* __restrict__ out, float* __restrict__ psum, float* __restrict__ psq) {
  int blk = blockIdx.x, tid = threadIdx.x;
  int view = blk / 9, q = blk % 9;
  int b = view / 81, uv = view % 81;
  int widx = q * 256 + tid;
  int j = widx % HH, i0 = (widx / HH) * 4;
  bool j0 = (j == 0), j95 = (j == 95);
  int base = j0 ? 0 : (j95 ? 92 : j - 1);
  float me0 = j0 ? 0.f : 1.f, me2 = j95 ? 0.f : 1.f;
  float mrow[6]; int roff[6];
  #pragma unroll
  for (int r6 = 0; r6 < 6; r6++) {
    int ii = i0 + r6 - 1;
    mrow[r6] = ((unsigned)ii < 96u) ? 1.f : 0.f;
    roff[r6] = min(max(ii, 0), 95) * HH + base;
  }
  float acc[4][7];
  #pragma unroll
  for (int px = 0; px < 4; px++)
    #pragma unroll
    for (int o = 0; o < 7; o++) acc[px][o] = 0.f;
  const float* ipbase = in + ((size_t)(b * 7)) * PLANE_F + uv * PLANE_A;
  float pre[6][3];
  #pragma unroll
  for (int r6 = 0; r6 < 6; r6++)
    row3sel(ipbase + roff[r6], 0, j0, j95, pre[r6][0], pre[r6][1], pre[r6][2]);
  #pragma unroll 1
  for (int c = 0; c < 7; c++) {
    float s = sc[c], h2 = sh[c];
    float win[6][3];
    #pragma unroll
    for (int r6 = 0; r6 < 6; r6++) {
      win[r6][0] = fmaxf(fmaf(pre[r6][0], s, h2), 0.f) * (mrow[r6] * me0);
      win[r6][1] = fmaxf(fmaf(pre[r6][1], s, h2), 0.f) * mrow[r6];
      win[r6][2] = fmaxf(fmaf(pre[r6][2], s, h2), 0.f) * (mrow[r6] * me2);
    }
    if (c < 6) {
      const float* ipn = ipbase + (size_t)(c + 1) * PLANE_F;
      #pragma unroll
      for (int r6 = 0; r6 < 6; r6++)
        row3sel(ipn + roff[r6], 0, j0, j95, pre[r6][0], pre[r6][1], pre[r6][2]);
    }
    #pragma unroll
    for (int o = 0; o < 7; o++) {
      const float* wc = w + (o * 7 + c) * 9;
      #pragma unroll
      for (int ky = 0; ky < 3; ky++)
        #pragma unroll
        for (int kx = 0; kx < 3; kx++) {
          float wv = wc[ky * 3 + kx];
          #pragma unroll
          for (int px = 0; px < 4; px++)
            acc[px][o] = fmaf(win[px + ky][kx], wv, acc[px][o]);
        }
    }
  }
  #pragma unroll
  for (int o = 0; o < 7; o++) {
    float* op = out + ((size_t)(b * 7 + o)) * PLANE_F + uv * PLANE_A + i0 * HH + j;
    #pragma unroll
    for (int px = 0; px < 4; px++) op[px * HH] = acc[px][o];
  }
  float sv[7], qv[7];
  #pragma unroll
  for (int o = 0; o < 7; o++) {
    sv[o] = acc[0][o] + acc[1][o] + acc[2][o] + acc[3][o];
    qv[o] = acc[0][o]*acc[0][o] + acc[1][o]*acc[1][o] + acc[2][o]*acc[2][o] + acc[3][o]*acc[3][o];
  }
  #pragma unroll
  for (int off2 = 32; off2 > 0; off2 >>= 1)
    #pragma unroll
    for (int o = 0; o < 7; o++) { sv[o] += __shfl_down(sv[o], off2); qv[o] += __shfl_down(qv[o], off2); }
  __shared__ float red[4][14];
  int wave = tid >> 6, lane = tid & 63;
  if (lane == 0) {
    #pragma unroll
    for (int o = 0; o < 7; o++) { red[wave][o] = sv[o]; red[wave][7 + o] = qv[o]; }
  }
  __syncthreads();
  if (tid < 14) {
    float t4 = red[0][tid] + red[1][tid] + red[2][tid] + red[3][tid];
    if (tid < 7) psum[tid * NBLK_FEAT + blk] = t4;
    else         psq[(tid - 7) * NBLK_FEAT + blk] = t4;
  }
}

// ===== BuildCost: 16-o, c-split halves, hoisted v-axis clamp/mask =====
// grid (9, 36, 4): x = g, y = pos block, z = b*2+half. Partial sums into cva/cvb.
// voff/mj hoisted (STATIC indexing only — unrolled v loop); ii/mi inline per (c,u).
__global__ __launch_bounds__(256) void k_buildcost(const float* __restrict__ F,
    const float* __restrict__ sc, const float* __restrict__ sh,
    const float* __restrict__ wt, float* __restrict__ cva, float* __restrict__ cvb) {
  int g = blockIdx.x, tid = threadIdx.x;
  int b = blockIdx.z >> 1, half = blockIdx.z & 1;
  int c0 = half ? 4 : 0;
  int ncu = half ? 27 : 36;
  int d = g - 4;
  bool flip = d > 0;
  int p = blockIdx.y * 256 + tid;
  int i = p / HH, j = p % HH;
  int voff[9]; float mj[9];
  #pragma unroll
  for (int v = 0; v < 9; v++) {
    int jj = j + d * (4 - v);
    mj[v] = ((unsigned)jj < 96u) ? 1.f : 0.f;
    voff[v] = v * PLANE_A + min(max(jj, 0), 95);
  }
  float acc[16];
  #pragma unroll
  for (int o = 0; o < 16; o++) acc[o] = 0.f;
  const float* Fb = F + ((size_t)(b * 7)) * PLANE_F;
  auto LD = [&](int c, int u, float* raw, float& mi) {
    int ii = i + d * (4 - u);
    mi = ((unsigned)ii < 96u) ? 1.f : 0.f;
    int iic = min(max(ii, 0), 95);
    const float* rowb = Fb + (size_t)c * PLANE_F + (u * 9) * PLANE_A + iic * HH;
    #pragma unroll
    for (int v = 0; v < 9; v++) raw[v] = rowb[voff[v]];
  };
  float raw[9], mi_pf;
  LD(c0, 0, raw, mi_pf);
  #pragma unroll 1
  for (int cu = 0; cu < ncu; cu++) {
    int c = c0 + cu / 9, u = cu % 9;
    float cr[9], mi = mi_pf;
    #pragma unroll
    for (int v = 0; v < 9; v++) cr[v] = raw[v];
    if (cu + 1 < ncu) {
      int cn = c0 + (cu + 1) / 9, un = (cu + 1) % 9;
      LD(cn, un, raw, mi_pf);
    }
    float s = sc[c], h2 = sh[c];
    int uw = flip ? 8 - u : u;
    const float* wbase = wt + ((size_t)((g * 7 + c) * 81 + uw * 9)) * 16;
    #pragma unroll
    for (int v = 0; v < 9; v++) {
      float a = fmaxf(fmaf(cr[v], s, h2), 0.f) * (mi * mj[v]);
      int vw = flip ? 8 - v : v;
      const float* wp = wbase + vw * 16;            // uniform -> s_load
      #pragma unroll
      for (int o = 0; o < 16; o++) acc[o] = fmaf(wp[o], a, acc[o]);
    }
  }
  float* cv = half ? cvb : cva;
  size_t cvbase = ((size_t)(b * 144 + g * 16)) * PLANE_A + p;
  #pragma unroll
  for (int o = 0; o < 16; o++) cv[cvbase + o * PLANE_A] = acc[o];
}

// ===== depthwise 3x3: 4-row strips, SGPR weights, fused BN prologue + stats =====
template<bool AFF, bool SUM2>
__global__ __launch_bounds__(256) void k_dwconv(const float* __restrict__ in,
    const float* __restrict__ in2, const float* __restrict__ w,
    const float* __restrict__ pps, const float* __restrict__ ppq,
    const float* __restrict__ g, const float* __restrict__ bbias,
    float* __restrict__ out, float* __restrict__ dps, float* __restrict__ dpq, int C) {
  int blk = blockIdx.x, tid = threadIdx.x;
  int q = blk % 9; int rr = blk / 9; int c = rr % C; int b = rr / C;
  __shared__ float scsh[2];
  float s = 1.f, h2 = 0.f;
  if (AFF) {
    float si = 0.f, qi = 0.f;
    if (tid < 64) {
      si = pps[c * 72 + tid]; qi = ppq[c * 72 + tid];
      if (tid < 8) { si += pps[c * 72 + 64 + tid]; qi += ppq[c * 72 + 64 + tid]; }
    }
    #pragma unroll
    for (int off = 32; off > 0; off >>= 1) { si += __shfl_down(si, off); qi += __shfl_down(qi, off); }
    if (tid == 0) {
      float mean = si * INV_NSMALL;
      float var = fmaxf(qi * INV_NSMALL - mean * mean, 0.f);
      float scale = g[c] / sqrtf(var + 1e-5f);
      scsh[0] = scale; scsh[1] = bbias[c] - mean * scale;
    }
    __syncthreads();
    s = scsh[0]; h2 = scsh[1];
  }
  int widx = q * 256 + tid;
  int j = widx % HH, i0 = (widx / HH) * 4;
  bool j0 = (j == 0), j95 = (j == 95);
  int base = j0 ? 0 : (j95 ? 92 : j - 1);
  float me0 = j0 ? 0.f : 1.f, me2 = j95 ? 0.f : 1.f;
  const float* wc = w + c * 9;                      // uniform -> s_load
  const float* ip = in + ((size_t)(b * C + c)) * PLANE_A;
  const float* ip2 = SUM2 ? in2 + ((size_t)(b * C + c)) * PLANE_A : nullptr;
  float win[6][3];
  #pragma unroll
  for (int r6 = 0; r6 < 6; r6++) {
    int ii = i0 + r6 - 1;
    float mi = ((unsigned)ii < 96u) ? 1.f : 0.f;
    int iic = min(max(ii, 0), 95);
    float w0, w1, w2;
    row3sel(ip + iic * HH, base, j0, j95, w0, w1, w2);
    if (SUM2) {
      float x0, x1, x2;
      row3sel(ip2 + iic * HH, base, j0, j95, x0, x1, x2);
      w0 += x0; w1 += x1; w2 += x2;
    }
    if (AFF) {
      w0 = fmaxf(fmaf(w0, s, h2), 0.f);
      w1 = fmaxf(fmaf(w1, s, h2), 0.f);
      w2 = fmaxf(fmaf(w2, s, h2), 0.f);
    }
    win[r6][0] = w0 * (mi * me0);
    win[r6][1] = w1 * mi;
    win[r6][2] = w2 * (mi * me2);
  }
  float acc[4];
  #pragma unroll
  for (int px = 0; px < 4; px++) acc[px] = 0.f;
  #pragma unroll
  for (int ky = 0; ky < 3; ky++)
    #pragma unroll
    for (int kx = 0; kx < 3; kx++) {
      float wv = wc[ky * 3 + kx];
      #pragma unroll
      for (int px = 0; px < 4; px++)
        acc[px] = fmaf(win[px + ky][kx], wv, acc[px]);
    }
  float* op = out + ((size_t)(b * C + c)) * PLANE_A + i0 * HH + j;
  #pragma unroll
  for (int px = 0; px < 4; px++) op[px * HH] = acc[px];
  float sv = acc[0] + acc[1] + acc[2] + acc[3];
  float qv = acc[0]*acc[0] + acc[1]*acc[1] + acc[2]*acc[2] + acc[3]*acc[3];
  #pragma unroll
  for (int off2 = 32; off2 > 0; off2 >>= 1) { sv += __shfl_down(sv, off2); qv += __shfl_down(qv, off2); }
  __shared__ float red[4][2];
  int wave = tid >> 6, lane = tid & 63;
  if (lane == 0) { red[wave][0] = sv; red[wave][1] = qv; }
  __syncthreads();
  if (tid == 0) {
    float S = red[0][0] + red[1][0] + red[2][0] + red[3][0];
    float Q = red[0][1] + red[1][1] + red[2][1] + red[3][1];
    dps[c * 18 + b * 9 + q] = S;
    dpq[c * 18 + b * 9 + q] = Q;
  }
}

// ===== pointwise conv: fused BN prologue (dps[c*18+k]) + 18 out/thread =====
template<int K>
__global__ __launch_bounds__(256) void k_pwconv(const float* __restrict__ in,
    const float* __restrict__ dps, const float* __restrict__ dpq,
    const float* __restrict__ g, const float* __restrict__ bbias,
    const float* __restrict__ wpt, float* __restrict__ out,
    float* __restrict__ pps, float* __restrict__ ppq) {
  int tid = threadIdx.x;
  __shared__ float2 scsh[K];
  if (tid < K) {
    float S = 0.f, Q = 0.f;
    #pragma unroll 1
    for (int k = 0; k < 18; k++) { S += dps[tid * 18 + k]; Q += dpq[tid * 18 + k]; }
    float mean = S * INV_NSMALL;
    float var = fmaxf(Q * INV_NSMALL - mean * mean, 0.f);
    float scale = g[tid] / sqrtf(var + 1e-5f);
    scsh[tid] = make_float2(scale, bbias[tid] - mean * scale);
  }
  __syncthreads();
  int posblk = blockIdx.y;
  int p = posblk * 256 + tid;
  int b = p / PLANE_A, pp = p - b * PLANE_A;
  int obase = blockIdx.x * 18;
  float acc[18];
  #pragma unroll
  for (int o = 0; o < 18; o++) acc[o] = 0.f;
  const float* ib = in + (size_t)b * K * PLANE_A + pp;
  float xn[4];
  #pragma unroll
  for (int q2 = 0; q2 < 4; q2++) xn[q2] = ib[(size_t)q2 * PLANE_A];
  #pragma unroll 1
  for (int c0 = 0; c0 < K; c0 += 4) {
    float xv[4];
    #pragma unroll
    for (int q2 = 0; q2 < 4; q2++) xv[q2] = xn[q2];
    if (c0 + 4 < K) {
      #pragma unroll
      for (int q2 = 0; q2 < 4; q2++) xn[q2] = ib[(size_t)(c0 + 4 + q2) * PLANE_A];
    }
    #pragma unroll
    for (int q2 = 0; q2 < 4; q2++) {
      int c = c0 + q2;
      float2 ss = scsh[c];
      float v = fmaxf(fmaf(xv[q2], ss.x, ss.y), 0.f);
      const float* wc = wpt + (size_t)c * 180 + obase;
      #pragma unroll
      for (int o = 0; o < 18; o++)
        acc[o] = fmaf(wc[o], v, acc[o]);
    }
  }
  #pragma unroll
  for (int o = 0; o < 18; o++)
    out[((size_t)(b * 180 + obase + o)) * PLANE_A + pp] = acc[o];
  __shared__ float rs[4][18], rq[4][18];
  int wave = tid >> 6, lane = tid & 63;
  #pragma unroll
  for (int o = 0; o < 18; o++) {
    float s = acc[o], q = acc[o] * acc[o];
    #pragma unroll
    for (int off = 32; off > 0; off >>= 1) { s += __shfl_down(s, off); q += __shfl_down(q, off); }
    if (lane == 0) { rs[wave][o] = s; rq[wave][o] = q; }
  }
  __syncthreads();
  if (tid < 18)
    pps[(obase + tid) * 72 + posblk] = rs[0][tid] + rs[1][tid] + rs[2][tid] + rs[3][tid];
  else if (tid < 36) {
    int o = tid - 18;
    ppq[(obase + o) * 72 + posblk] = rq[0][o] + rq[1][o] + rq[2][o] + rq[3][o];
  }
}

// ===== final: fused BN prologue + 1x1 180->9 + softmax + E[d] =====
__global__ __launch_bounds__(256) void k_final(const float* __restrict__ in,
    const float* __restrict__ dps, const float* __restrict__ dpq,
    const float* __restrict__ g, const float* __restrict__ bbias,
    const float* __restrict__ wpt, float* __restrict__ out) {
  int tid = threadIdx.x;
  __shared__ float2 scsh[180];
  if (tid < 180) {
    float S = 0.f, Q = 0.f;
    #pragma unroll 1
    for (int k = 0; k < 18; k++) { S += dps[tid * 18 + k]; Q += dpq[tid * 18 + k]; }
    float mean = S * INV_NSMALL;
    float var = fmaxf(Q * INV_NSMALL - mean * mean, 0.f);
    float scale = g[tid] / sqrtf(var + 1e-5f);
    scsh[tid] = make_float2(scale, bbias[tid] - mean * scale);
  }
  __syncthreads();
  int t = blockIdx.x * 256 + tid;
  int b = t / PLANE_A, p = t - b * PLANE_A;
  const float* ib = in + (size_t)b * 180 * PLANE_A + p;
  float acc[9];
  #pragma unroll
  for (int o = 0; o < 9; o++) acc[o] = 0.f;
  float xn[4];
  #pragma unroll
  for (int q2 = 0; q2 < 4; q2++) xn[q2] = ib[(size_t)q2 * PLANE_A];
  #pragma unroll 1
  for (int c0 = 0; c0 < 180; c0 += 4) {
    float xv[4];
    #pragma unroll
    for (int q2 = 0; q2 < 4; q2++) xv[q2] = xn[q2];
    if (c0 + 4 < 180) {
      #pragma unroll
      for (int q2 = 0; q2 < 4; q2++) xn[q2] = ib[(size_t)(c0 + 4 + q2) * PLANE_A];
    }
    #pragma unroll
    for (int q2 = 0; q2 < 4; q2++) {
      int c = c0 + q2;
      float2 ss = scsh[c];
      float v = fmaxf(fmaf(xv[q2], ss.x, ss.y), 0.f);
      const float* wc = wpt + (size_t)c * 9;
      #pragma unroll
      for (int o = 0; o < 9; o++) acc[o] = fmaf(wc[o], v, acc[o]);
    }
  }
  float m = acc[0];
  #pragma unroll
  for (int o = 1; o < 9; o++) m = fmaxf(m, acc[o]);
  float se = 0.f, num = 0.f;
  #pragma unroll
  for (int o = 0; o < 9; o++) {
    float e = expf(acc[o] - m);
    se += e;
    num += (float)(o - 4) * e;
  }
  out[t] = num / se;
}

extern "C" void kernel_launch(void* const* d_in, const int* in_sizes, int n_in,
                              void* d_out, int out_size, void* d_ws, size_t ws_size,
                              hipStream_t stream) {
  const float* x    = (const float*)d_in[0];
  const float* fw0  = (const float*)d_in[1];
  const float* fg0  = (const float*)d_in[2];
  const float* fb0  = (const float*)d_in[3];
  const float* fw   = (const float*)d_in[4];
  const float* fg   = (const float*)d_in[5];
  const float* fb   = (const float*)d_in[6];
  const float* bcw  = (const float*)d_in[7];
  const float* a0dw = (const float*)d_in[8];
  const float* a0dg = (const float*)d_in[9];
  const float* a0db = (const float*)d_in[10];
  const float* a0pw = (const float*)d_in[11];
  const float* a0pg = (const float*)d_in[12];
  const float* a0pb = (const float*)d_in[13];
  const float* amdw = (const float*)d_in[14];
  const float* amdg = (const float*)d_in[15];
  const float* amdb = (const float*)d_in[16];
  const float* ampw = (const float*)d_in[17];
  const float* ampg = (const float*)d_in[18];
  const float* ampb = (const float*)d_in[19];
  const float* ldw  = (const float*)d_in[20];
  const float* ldg  = (const float*)d_in[21];
  const float* ldb  = (const float*)d_in[22];
  const float* lpw  = (const float*)d_in[23];
  float* outp = (float*)d_out;

  float* FA    = (float*)d_ws;
  float* FB    = FA + (size_t)BB * 7 * PLANE_F;
  float* CVA   = FB + (size_t)BB * 7 * PLANE_F;
  float* CVB   = CVA + (size_t)BB * 144 * PLANE_A;
  float* GA    = CVB + (size_t)BB * 144 * PLANE_A;
  float* GB    = GA + (size_t)BB * 180 * PLANE_A;
  float* PSUM  = GB + (size_t)BB * 180 * PLANE_A;
  float* PSQ   = PSUM + 180 * 288;
  float* PPS   = PSQ + 180 * 288;
  float* PPQ   = PPS + 180 * 72;
  float* SC    = PPQ + 180 * 72;
  float* SH    = SC + 180;
  float* WT    = SH + 180;
  float* WPT   = WT + 81648;
  float* WPT_A0 = WPT;
  float* WPT_AM = WPT + 25920;
  float* WPT_L  = WPT + 25920 + 129600;

  const float invNbig = 1.0f / (float)(BB * PLANE_F);

  k_wprep<<<(238788 + 255) / 256, 256, 0, stream>>>(bcw, a0pw, ampw, lpw, WT, WPT);

  k_featconv0<<<NBLK_FEAT, 256, 0, stream>>>(x, fw0, FA, PSUM, PSQ);
  k_bnfinal<<<7, 256, 0, stream>>>(PSUM, PSQ, fg0, fb0, SC, SH, NBLK_FEAT, invNbig);

  float* cur = FA; float* nxt = FB;
  for (int i = 0; i < 6; i++) {
    k_featconv4<<<NBLK_FEAT, 256, 0, stream>>>(cur, fw + i * 441, SC, SH, nxt, PSUM, PSQ);
    k_bnfinal<<<7, 256, 0, stream>>>(PSUM, PSQ, fg + i * 7, fb + i * 7, SC, SH, NBLK_FEAT, invNbig);
    float* tmp = cur; cur = nxt; nxt = tmp;
  }

  k_buildcost<<<dim3(9, 36, 4), 256, 0, stream>>>(cur, SC, SH, WT, CVA, CVB);

  k_dwconv<false, true><<<BB * 144 * 9, 256, 0, stream>>>(CVA, CVB, a0dw,
      nullptr, nullptr, nullptr, nullptr, GA, PSUM, PSQ, 144);
  k_pwconv<144><<<dim3(10, 72), 256, 0, stream>>>(GA, PSUM, PSQ, a0dg, a0db,
      WPT_A0, GB, PPS, PPQ);

  for (int m = 0; m < 4; m++) {
    const float* pg = (m == 0) ? a0pg : ampg + (m - 1) * 180;
    const float* pb = (m == 0) ? a0pb : ampb + (m - 1) * 180;
    k_dwconv<true, false><<<BB * 180 * 9, 256, 0, stream>>>(GB, nullptr, amdw + m * 1620,
        PPS, PPQ, pg, pb, GA, PSUM, PSQ, 180);
    k_pwconv<180><<<dim3(10, 72), 256, 0, stream>>>(GA, PSUM, PSQ,
        amdg + m * 180, amdb + m * 180, WPT_AM + m * 32400, GB, PPS, PPQ);
  }

  k_dwconv<true, false><<<BB * 180 * 9, 256, 0, stream>>>(GB, nullptr, ldw,
      PPS, PPQ, ampg + 540, ampb + 540, GA, PSUM, PSQ, 180);

  k_final<<<72, 256, 0, stream>>>(GA, PSUM, PSQ, ldg, ldb, WPT_L, outp);
}